// Round 1
// baseline (288.649 us; speedup 1.0000x reference)
//
#include <hip/hip_runtime.h>

typedef __attribute__((ext_vector_type(4))) float  f32x4;
typedef __attribute__((ext_vector_type(8))) short  s16x8;

#define DEVI __device__ __forceinline__

// ---------------- constants ----------------
constexpr int Bb   = 2;
constexpr int Nn   = 2048;
constexpr int DIMc = 1024;
constexpr int Hh   = 16;
constexpr int DHc  = 64;
constexpr int CTXN = 256;
constexpr int Jv   = Nn + 1 + CTXN;   // 2305 valid kv tokens
constexpr int JP   = 2368;            // padded to 37*64
constexpr int QKVN = Hh*DHc + 2*DHc;  // 1152

// ---------------- helpers ----------------
DEVI unsigned short f2bf(float f) {
    union { float f; unsigned u; } v; v.f = f;
    unsigned r = v.u + 0x7fffu + ((v.u >> 16) & 1u);
    return (unsigned short)(r >> 16);
}
DEVI float bf2f(unsigned short h) {
    union { unsigned u; float f; } v; v.u = ((unsigned)h) << 16;
    return v.f;
}

// ---------------- transpose f32 [R][C] -> bf16 [C][R], with scale ----------------
__global__ __launch_bounds__(256) void k_transpose(const float* __restrict__ in,
                                                   unsigned short* __restrict__ out,
                                                   int R, int C, float scale) {
    __shared__ float tile[32][33];
    int tx = threadIdx.x & 31, ty = threadIdx.x >> 5;   // 32 x 8
    int r0 = blockIdx.y * 32, c0 = blockIdx.x * 32;
#pragma unroll
    for (int i = 0; i < 32; i += 8)
        tile[ty + i][tx] = in[(size_t)(r0 + ty + i) * C + c0 + tx];
    __syncthreads();
#pragma unroll
    for (int i = 0; i < 32; i += 8)
        out[(size_t)(c0 + ty + i) * R + r0 + tx] = f2bf(tile[tx][ty + i] * scale);
}

// ---------------- LayerNorm, 1024 cols, 256 threads/row ----------------
template<bool BETA, bool OUT_BF16>
__global__ __launch_bounds__(256) void k_ln(const float* __restrict__ in,
                                            const float* __restrict__ g,
                                            const float* __restrict__ b,
                                            void* __restrict__ out, float eps) {
    int row = blockIdx.x, tid = threadIdx.x;
    const float* rp = in + (size_t)row * 1024;
    f32x4 v = *(const f32x4*)(rp + tid * 4);
    float s = v.x + v.y + v.z + v.w;
    float q = v.x * v.x + v.y * v.y + v.z * v.z + v.w * v.w;
#pragma unroll
    for (int m = 32; m; m >>= 1) { s += __shfl_down(s, m, 64); q += __shfl_down(q, m, 64); }
    __shared__ float ss[4], sq[4];
    int wid = tid >> 6, lane = tid & 63;
    if (lane == 0) { ss[wid] = s; sq[wid] = q; }
    __syncthreads();
    s = ss[0] + ss[1] + ss[2] + ss[3];
    q = sq[0] + sq[1] + sq[2] + sq[3];
    float mean = s * (1.0f / 1024.0f);
    float var  = q * (1.0f / 1024.0f) - mean * mean;
    float rstd = rsqrtf(var + eps);
    f32x4 gg = *(const f32x4*)(g + tid * 4);
    f32x4 r;
#pragma unroll
    for (int e = 0; e < 4; e++) r[e] = (v[e] - mean) * rstd * gg[e];
    if (BETA) {
        f32x4 bb = *(const f32x4*)(b + tid * 4);
#pragma unroll
        for (int e = 0; e < 4; e++) r[e] += bb[e];
    }
    if (OUT_BF16) {
        unsigned short o[4];
#pragma unroll
        for (int e = 0; e < 4; e++) o[e] = f2bf(r[e]);
        *(uint2*)((unsigned short*)out + (size_t)row * 1024 + tid * 4) = *(const uint2*)o;
    } else {
        *(f32x4*)((float*)out + (size_t)row * 1024 + tid * 4) = r;
    }
}

// ---------------- GEMM: C[M][N] = A[M][K](bf16) * BT[N][K](bf16)^T ----------------
// 128x128 tile, BK=64, 256 threads = 4 waves (2x2), each wave 64x64 (4x4 frags)
template<int OUT_BF16>
__global__ __launch_bounds__(256) void k_gemm_bt(const unsigned short* __restrict__ A,
                                                 const unsigned short* __restrict__ BT,
                                                 void* __restrict__ C,
                                                 int M, int N, int K) {
    __shared__ unsigned short Al[128][72];
    __shared__ unsigned short Bl[128][72];
    int tid = threadIdx.x;
    int bn = blockIdx.x, bm = blockIdx.y;
    int wid = tid >> 6, lane = tid & 63;
    int wm = wid >> 1, wn = wid & 1;
    int lr = lane & 15, lg = lane >> 4;

    f32x4 acc[4][4] = {};
    for (int k0 = 0; k0 < K; k0 += 64) {
        __syncthreads();
#pragma unroll
        for (int i = 0; i < 4; i++) {
            int s = tid + 256 * i;
            int row = s >> 3, c8 = (s & 7) * 8;
            *(s16x8*)&Al[row][c8] = *(const s16x8*)(A  + (size_t)(bm * 128 + row) * K + k0 + c8);
            *(s16x8*)&Bl[row][c8] = *(const s16x8*)(BT + (size_t)(bn * 128 + row) * K + k0 + c8);
        }
        __syncthreads();
#pragma unroll
        for (int kk = 0; kk < 2; kk++) {
            s16x8 af[4], bf[4];
#pragma unroll
            for (int mi = 0; mi < 4; mi++)
                af[mi] = *(const s16x8*)&Al[wm * 64 + mi * 16 + lr][kk * 32 + lg * 8];
#pragma unroll
            for (int ni = 0; ni < 4; ni++)
                bf[ni] = *(const s16x8*)&Bl[wn * 64 + ni * 16 + lr][kk * 32 + lg * 8];
#pragma unroll
            for (int mi = 0; mi < 4; mi++)
#pragma unroll
                for (int ni = 0; ni < 4; ni++)
                    acc[mi][ni] = __builtin_amdgcn_mfma_f32_16x16x32_bf16(af[mi], bf[ni], acc[mi][ni], 0, 0, 0);
        }
    }
#pragma unroll
    for (int mi = 0; mi < 4; mi++)
#pragma unroll
        for (int r = 0; r < 4; r++) {
            int row = bm * 128 + wm * 64 + mi * 16 + lg * 4 + r;
#pragma unroll
            for (int ni = 0; ni < 4; ni++) {
                int col = bn * 128 + wn * 64 + ni * 16 + lr;
                float val = acc[mi][ni][r];
                if (OUT_BF16)
                    ((unsigned short*)C)[(size_t)row * N + col] = f2bf(val);
                else
                    ((float*)C)[(size_t)row * N + col] = val;
            }
        }
}

// ---------------- assemble K/V: self tokens + null + context, pad to JP ----------------
__global__ __launch_bounds__(256) void k_assemble_kv(const unsigned short* __restrict__ qkv,
                                                     const unsigned short* __restrict__ ckv,
                                                     const float* __restrict__ nkv,
                                                     const float* __restrict__ bc,
                                                     unsigned short* __restrict__ Kb,
                                                     unsigned short* __restrict__ Vb) {
    int idx = blockIdx.x * 256 + threadIdx.x;   // Bb*JP*64 total
    int d = idx & 63;
    int j = (idx >> 6) % JP;
    int b = idx / (64 * JP);
    float kv, vv;
    if (j < Nn) {
        const unsigned short* r = qkv + (size_t)(b * Nn + j) * QKVN + Hh * DHc;
        kv = bf2f(r[d]); vv = bf2f(r[64 + d]);
    } else if (j == Nn) {
        kv = nkv[d]; vv = nkv[64 + d];
    } else if (j < Jv) {
        const unsigned short* r = ckv + (size_t)(b * CTXN + (j - Nn - 1)) * 128;
        kv = bf2f(r[d]) + bc[d]; vv = bf2f(r[64 + d]) + bc[64 + d];
    } else {
        kv = 0.0f; vv = 0.0f;
    }
    Kb[((size_t)b * JP + j) * 64 + d] = f2bf(kv);
    Vb[((size_t)b * JP + j) * 64 + d] = f2bf(vv);
}

// ---------------- flash attention ----------------
// grid: b(2) x h(16) x qtile(32).  block = 256 = 4 waves, wave owns 16 q-rows.
__global__ __launch_bounds__(256) void k_attn(const unsigned short* __restrict__ qkv,
                                              const unsigned short* __restrict__ Kb,
                                              const unsigned short* __restrict__ Vb,
                                              unsigned short* __restrict__ aout) {
    __shared__ unsigned short Kl[64][72];
    __shared__ unsigned short Vl[64][72];     // transposed: Vl[d][j]
    __shared__ unsigned short Pl[4][16][72];  // per-wave P tile [i][j]

    int bid = blockIdx.x;
    int qt = bid & 31, h = (bid >> 5) & 15, b = bid >> 9;
    int tid = threadIdx.x, wid = tid >> 6, lane = tid & 63;
    int lr = lane & 15, lg = lane >> 4;
    int n0 = qt * 64 + wid * 16;

    // Q fragments (A-layout): row = lr, k = kk*32 + lg*8 + e
    s16x8 qf[2];
#pragma unroll
    for (int kk = 0; kk < 2; kk++)
        qf[kk] = *(const s16x8*)(qkv + (size_t)(b * Nn + n0 + lr) * QKVN + h * 64 + kk * 32 + lg * 8);

    f32x4 O[4] = {};
    float Mv[4], Lv[4];
#pragma unroll
    for (int r = 0; r < 4; r++) { Mv[r] = -1e30f; Lv[r] = 0.0f; }

    const unsigned short* Kbb = Kb + (size_t)b * JP * 64;
    const unsigned short* Vbb = Vb + (size_t)b * JP * 64;

    for (int j0 = 0; j0 < JP; j0 += 64) {
        __syncthreads();   // prev-iter LDS reads done
#pragma unroll
        for (int i = 0; i < 2; i++) {
            int s = tid + 256 * i;
            int row = s >> 3, c8 = (s & 7) * 8;
            *(s16x8*)&Kl[row][c8] = *(const s16x8*)(Kbb + (size_t)(j0 + row) * 64 + c8);
            s16x8 vv = *(const s16x8*)(Vbb + (size_t)(j0 + row) * 64 + c8);
#pragma unroll
            for (int e = 0; e < 8; e++) Vl[c8 + e][row] = (unsigned short)vv[e];
        }
        __syncthreads();

        // S = Q K^T  (B-operand frag: col j = lr -> K row)
        f32x4 sf[4] = {};
#pragma unroll
        for (int kk = 0; kk < 2; kk++)
#pragma unroll
            for (int jf = 0; jf < 4; jf++) {
                s16x8 kf = *(const s16x8*)&Kl[jf * 16 + lr][kk * 32 + lg * 8];
                sf[jf] = __builtin_amdgcn_mfma_f32_16x16x32_bf16(qf[kk], kf, sf[jf], 0, 0, 0);
            }
        // mask padded tokens
#pragma unroll
        for (int jf = 0; jf < 4; jf++) {
            int jg = j0 + jf * 16 + lr;
            if (jg >= Jv) {
#pragma unroll
                for (int r = 0; r < 4; r++) sf[jf][r] = -1e30f;
            }
        }
        // online softmax (rows = lg*4 + r; reduce over 16 lanes of group)
#pragma unroll
        for (int r = 0; r < 4; r++) {
            float mx = fmaxf(fmaxf(sf[0][r], sf[1][r]), fmaxf(sf[2][r], sf[3][r]));
#pragma unroll
            for (int m = 1; m < 16; m <<= 1) mx = fmaxf(mx, __shfl_xor(mx, m, 64));
            float mnew = fmaxf(Mv[r], mx);
            float sum = 0.0f;
#pragma unroll
            for (int jf = 0; jf < 4; jf++) {
                float p = __expf(sf[jf][r] - mnew);
                sf[jf][r] = p;
                sum += p;
            }
#pragma unroll
            for (int m = 1; m < 16; m <<= 1) sum += __shfl_xor(sum, m, 64);
            float alpha = __expf(Mv[r] - mnew);
            Lv[r] = Lv[r] * alpha + sum;
#pragma unroll
            for (int df = 0; df < 4; df++) O[df][r] *= alpha;
            Mv[r] = mnew;
        }
        // P -> LDS (C-layout -> A-layout round trip), intra-wave
#pragma unroll
        for (int jf = 0; jf < 4; jf++)
#pragma unroll
            for (int r = 0; r < 4; r++)
                Pl[wid][lg * 4 + r][jf * 16 + lr] = f2bf(sf[jf][r]);
        // PV
#pragma unroll
        for (int kk = 0; kk < 2; kk++) {
            s16x8 pa = *(const s16x8*)&Pl[wid][lr][kk * 32 + lg * 8];
#pragma unroll
            for (int df = 0; df < 4; df++) {
                s16x8 vf = *(const s16x8*)&Vl[df * 16 + lr][kk * 32 + lg * 8];
                O[df] = __builtin_amdgcn_mfma_f32_16x16x32_bf16(pa, vf, O[df], 0, 0, 0);
            }
        }
    }
    // write attention output [b][n][h*64+d] bf16
#pragma unroll
    for (int df = 0; df < 4; df++)
#pragma unroll
        for (int r = 0; r < 4; r++) {
            int n = n0 + lg * 4 + r;
            aout[(size_t)(b * Nn + n) * 1024 + h * 64 + df * 16 + lr] = f2bf(O[df][r] / Lv[r]);
        }
}

// ---------------- launch ----------------
extern "C" void kernel_launch(void* const* d_in, const int* in_sizes, int n_in,
                              void* d_out, int out_size, void* d_ws, size_t ws_size,
                              hipStream_t stream) {
    const float* x    = (const float*)d_in[0];
    const float* ctx  = (const float*)d_in[1];
    const float* g1   = (const float*)d_in[2];
    const float* Wq   = (const float*)d_in[3];
    const float* Wkv  = (const float*)d_in[4];
    const float* nkv  = (const float*)d_in[5];
    const float* ctxg = (const float*)d_in[6];
    const float* ctxb = (const float*)d_in[7];
    const float* Wc   = (const float*)d_in[8];
    const float* bc   = (const float*)d_in[9];
    const float* Wout = (const float*)d_in[10];
    const float* g2   = (const float*)d_in[11];
    float* out = (float*)d_out;

    char* w = (char*)d_ws;
    unsigned short* h_    = (unsigned short*)w; w += (size_t)4096 * 1024 * 2;
    unsigned short* ch    = (unsigned short*)w; w += (size_t)512 * 1024 * 2;
    unsigned short* WqkvT = (unsigned short*)w; w += (size_t)1152 * 1024 * 2;
    unsigned short* WcT   = (unsigned short*)w; w += (size_t)128 * 1024 * 2;
    unsigned short* WoutT = (unsigned short*)w; w += (size_t)1024 * 1024 * 2;
    unsigned short* qkv   = (unsigned short*)w; w += (size_t)4096 * 1152 * 2;
    unsigned short* ckv   = (unsigned short*)w; w += (size_t)512 * 128 * 2;
    unsigned short* Kb    = (unsigned short*)w; w += (size_t)Bb * JP * 64 * 2;
    unsigned short* Vb    = (unsigned short*)w; w += (size_t)Bb * JP * 64 * 2;
    unsigned short* aout  = (unsigned short*)w; w += (size_t)4096 * 1024 * 2;
    float* preout         = (float*)w;          w += (size_t)4096 * 1024 * 4;

    const float qscale = 0.125f;  // DH^-0.5

    // weight transposes (f32 -> bf16, B^T layout)
    k_transpose<<<dim3(32, 32), 256, 0, stream>>>(Wq,   WqkvT,                 1024, 1024, qscale);
    k_transpose<<<dim3(4,  32), 256, 0, stream>>>(Wkv,  WqkvT + 1024 * 1024,   1024, 128,  1.0f);
    k_transpose<<<dim3(4,  32), 256, 0, stream>>>(Wc,   WcT,                   1024, 128,  1.0f);
    k_transpose<<<dim3(32, 32), 256, 0, stream>>>(Wout, WoutT,                 1024, 1024, 1.0f);

    // layernorms
    k_ln<false, true><<<4096, 256, 0, stream>>>(x,   g1,   nullptr, h_, 1e-5f);
    k_ln<true,  true><<<512,  256, 0, stream>>>(ctx, ctxg, ctxb,    ch, 1e-6f);

    // projections
    k_gemm_bt<1><<<dim3(9, 32), 256, 0, stream>>>(h_, WqkvT, qkv, 4096, 1152, 1024);
    k_gemm_bt<1><<<dim3(1, 4),  256, 0, stream>>>(ch, WcT,   ckv, 512,  128,  1024);

    // build K/V (with null token, context bias, zero padding)
    k_assemble_kv<<<(Bb * JP * 64) / 256, 256, 0, stream>>>(qkv, ckv, nkv, bc, Kb, Vb);

    // attention
    k_attn<<<Bb * Hh * (Nn / 64), 256, 0, stream>>>(qkv, Kb, Vb, aout);

    // output projection + final LN
    k_gemm_bt<0><<<dim3(8, 32), 256, 0, stream>>>(aout, WoutT, preout, 4096, 1024, 1024);
    k_ln<false, false><<<4096, 256, 0, stream>>>(preout, g2, nullptr, out, 1e-5f);
}

// Round 2
// 190.499 us; speedup vs baseline: 1.5152x; 1.5152x over previous
//
#include <hip/hip_runtime.h>

typedef __attribute__((ext_vector_type(4))) float  f32x4;
typedef __attribute__((ext_vector_type(8))) short  s16x8;

#define DEVI __device__ __forceinline__

// ---------------- constants ----------------
constexpr int Bb   = 2;
constexpr int Nn   = 2048;
constexpr int Hh   = 16;
constexpr int DHc  = 64;
constexpr int CTXN = 256;
constexpr int Jv   = Nn + 1 + CTXN;   // 2305 valid kv tokens
constexpr int JP   = 2368;            // padded to 37*64
constexpr int QKVN = Hh*DHc + 2*DHc;  // 1152

// ---------------- helpers ----------------
DEVI unsigned short f2bf(float f) {
    union { float f; unsigned u; } v; v.f = f;
    unsigned r = v.u + 0x7fffu + ((v.u >> 16) & 1u);
    return (unsigned short)(r >> 16);
}
DEVI float bf2f(unsigned short h) {
    union { unsigned u; float f; } v; v.u = ((unsigned)h) << 16;
    return v.f;
}
DEVI unsigned pack_bf(float lo, float hi) {
    return (unsigned)f2bf(lo) | ((unsigned)f2bf(hi) << 16);
}

// ---------------- transpose f32 [R][C] -> bf16 [C][R], with scale ----------------
__global__ __launch_bounds__(256) void k_transpose(const float* __restrict__ in,
                                                   unsigned short* __restrict__ out,
                                                   int R, int C, float scale) {
    __shared__ float tile[32][33];
    int tx = threadIdx.x & 31, ty = threadIdx.x >> 5;   // 32 x 8
    int r0 = blockIdx.y * 32, c0 = blockIdx.x * 32;
#pragma unroll
    for (int i = 0; i < 32; i += 8)
        tile[ty + i][tx] = in[(size_t)(r0 + ty + i) * C + c0 + tx];
    __syncthreads();
#pragma unroll
    for (int i = 0; i < 32; i += 8)
        out[(size_t)(c0 + ty + i) * R + r0 + tx] = f2bf(tile[tx][ty + i] * scale);
}

// ---------------- LayerNorm, 1024 cols, 256 threads/row ----------------
template<bool BETA, bool OUT_BF16>
__global__ __launch_bounds__(256) void k_ln(const float* __restrict__ in,
                                            const float* __restrict__ g,
                                            const float* __restrict__ b,
                                            void* __restrict__ out, float eps) {
    int row = blockIdx.x, tid = threadIdx.x;
    const float* rp = in + (size_t)row * 1024;
    f32x4 v = *(const f32x4*)(rp + tid * 4);
    float s = v.x + v.y + v.z + v.w;
    float q = v.x * v.x + v.y * v.y + v.z * v.z + v.w * v.w;
#pragma unroll
    for (int m = 32; m; m >>= 1) { s += __shfl_down(s, m, 64); q += __shfl_down(q, m, 64); }
    __shared__ float ss[4], sq[4];
    int wid = tid >> 6, lane = tid & 63;
    if (lane == 0) { ss[wid] = s; sq[wid] = q; }
    __syncthreads();
    s = ss[0] + ss[1] + ss[2] + ss[3];
    q = sq[0] + sq[1] + sq[2] + sq[3];
    float mean = s * (1.0f / 1024.0f);
    float var  = q * (1.0f / 1024.0f) - mean * mean;
    float rstd = rsqrtf(var + eps);
    f32x4 gg = *(const f32x4*)(g + tid * 4);
    f32x4 r;
#pragma unroll
    for (int e = 0; e < 4; e++) r[e] = (v[e] - mean) * rstd * gg[e];
    if (BETA) {
        f32x4 bb = *(const f32x4*)(b + tid * 4);
#pragma unroll
        for (int e = 0; e < 4; e++) r[e] += bb[e];
    }
    if (OUT_BF16) {
        unsigned short o[4];
#pragma unroll
        for (int e = 0; e < 4; e++) o[e] = f2bf(r[e]);
        *(uint2*)((unsigned short*)out + (size_t)row * 1024 + tid * 4) = *(const uint2*)o;
    } else {
        *(f32x4*)((float*)out + (size_t)row * 1024 + tid * 4) = r;
    }
}

// ---------------- GEMM: C[M][N] = A[M][K](bf16) * BT[N][K](bf16)^T ----------------
template<int OUT_BF16>
__global__ __launch_bounds__(256) void k_gemm_bt(const unsigned short* __restrict__ A,
                                                 const unsigned short* __restrict__ BT,
                                                 void* __restrict__ C,
                                                 int M, int N, int K) {
    __shared__ unsigned short Al[128][72];
    __shared__ unsigned short Bl[128][72];
    int tid = threadIdx.x;
    int bn = blockIdx.x, bm = blockIdx.y;
    int wid = tid >> 6, lane = tid & 63;
    int wm = wid >> 1, wn = wid & 1;
    int lr = lane & 15, lg = lane >> 4;

    f32x4 acc[4][4] = {};
    for (int k0 = 0; k0 < K; k0 += 64) {
        __syncthreads();
#pragma unroll
        for (int i = 0; i < 4; i++) {
            int s = tid + 256 * i;
            int row = s >> 3, c8 = (s & 7) * 8;
            *(s16x8*)&Al[row][c8] = *(const s16x8*)(A  + (size_t)(bm * 128 + row) * K + k0 + c8);
            *(s16x8*)&Bl[row][c8] = *(const s16x8*)(BT + (size_t)(bn * 128 + row) * K + k0 + c8);
        }
        __syncthreads();
#pragma unroll
        for (int kk = 0; kk < 2; kk++) {
            s16x8 af[4], bf[4];
#pragma unroll
            for (int mi = 0; mi < 4; mi++)
                af[mi] = *(const s16x8*)&Al[wm * 64 + mi * 16 + lr][kk * 32 + lg * 8];
#pragma unroll
            for (int ni = 0; ni < 4; ni++)
                bf[ni] = *(const s16x8*)&Bl[wn * 64 + ni * 16 + lr][kk * 32 + lg * 8];
#pragma unroll
            for (int mi = 0; mi < 4; mi++)
#pragma unroll
                for (int ni = 0; ni < 4; ni++)
                    acc[mi][ni] = __builtin_amdgcn_mfma_f32_16x16x32_bf16(af[mi], bf[ni], acc[mi][ni], 0, 0, 0);
        }
    }
#pragma unroll
    for (int mi = 0; mi < 4; mi++)
#pragma unroll
        for (int r = 0; r < 4; r++) {
            int row = bm * 128 + wm * 64 + mi * 16 + lg * 4 + r;
#pragma unroll
            for (int ni = 0; ni < 4; ni++) {
                int col = bn * 128 + wn * 64 + ni * 16 + lr;
                float val = acc[mi][ni][r];
                if (OUT_BF16)
                    ((unsigned short*)C)[(size_t)row * N + col] = f2bf(val);
                else
                    ((float*)C)[(size_t)row * N + col] = val;
            }
        }
}

// ---------------- assemble K (row-major [b][j][d]) and V^T ([b][d][JP]) ----------------
__global__ __launch_bounds__(256) void k_assemble_kv(const unsigned short* __restrict__ qkv,
                                                     const unsigned short* __restrict__ ckv,
                                                     const float* __restrict__ nkv,
                                                     const float* __restrict__ bc,
                                                     unsigned short* __restrict__ Kb,
                                                     unsigned short* __restrict__ Vt) {
    int idx = blockIdx.x * 256 + threadIdx.x;   // Bb*JP*64 total
    int d = idx & 63;
    int j = (idx >> 6) % JP;
    int b = idx / (64 * JP);
    float kv, vv;
    if (j < Nn) {
        const unsigned short* r = qkv + (size_t)(b * Nn + j) * QKVN + Hh * DHc;
        kv = bf2f(r[d]); vv = bf2f(r[64 + d]);
    } else if (j == Nn) {
        kv = nkv[d]; vv = nkv[64 + d];
    } else if (j < Jv) {
        const unsigned short* r = ckv + (size_t)(b * CTXN + (j - Nn - 1)) * 128;
        kv = bf2f(r[d]) + bc[d]; vv = bf2f(r[64 + d]) + bc[64 + d];
    } else {
        kv = 0.0f; vv = 0.0f;
    }
    Kb[((size_t)b * JP + j) * 64 + d] = f2bf(kv);
    Vt[((size_t)b * 64 + d) * JP + j] = f2bf(vv);
}

// ---------------- flash attention (swapped-operand scheme) ----------------
// grid: b(2) x h(16) x qtile(32).  block = 256 = 4 waves; wave owns 16 q-rows (q = n0 + lr).
__global__ __launch_bounds__(256) void k_attn(const unsigned short* __restrict__ qkv,
                                              const unsigned short* __restrict__ Kb,
                                              const unsigned short* __restrict__ Vt,
                                              unsigned short* __restrict__ aout) {
    __shared__ unsigned short Kl[64][72];   // K rows [j][d]
    __shared__ unsigned short Vl[64][72];   // V^T rows [d][j]
    __shared__ unsigned       Pp[4][16][34]; // per-wave packed P^T: row=q-local, 32 bf16x2 pairs

    int bid = blockIdx.x;
    int qt = bid & 31, h = (bid >> 5) & 15, b = bid >> 9;
    int tid = threadIdx.x, wid = tid >> 6, lane = tid & 63;
    int lr = lane & 15, lg = lane >> 4;
    int n0 = qt * 64 + wid * 16;

    // Q fragments (B-operand): col=lr -> q row n0+lr, k = kk*32 + lg*8 + e
    s16x8 qf[2];
#pragma unroll
    for (int kk = 0; kk < 2; kk++)
        qf[kk] = *(const s16x8*)(qkv + (size_t)(b * Nn + n0 + lr) * QKVN + h * 64 + kk * 32 + lg * 8);

    f32x4 O[4] = {};        // O^T frags: col=lr=q, row d = df*16 + lg*4 + r
    float Mv = -1e30f, Lv = 0.0f;

    const unsigned short* Kbb = Kb + (size_t)b * JP * 64;
    const unsigned short* Vbb = Vt + (size_t)b * 64 * JP;

    int pbase = ((2 * lg) & 3) * 8 + (lg >> 1) * 2;
    unsigned* pwr = &Pp[wid][lr][lg * 8];
    const unsigned* prd = &Pp[wid][lr][0];

    for (int j0 = 0; j0 < JP; j0 += 64) {
        __syncthreads();   // prev-iter LDS reads done
#pragma unroll
        for (int i = 0; i < 2; i++) {
            int s = tid + 256 * i;
            int row = s >> 3, c8 = (s & 7) * 8;
            *(s16x8*)&Kl[row][c8] = *(const s16x8*)(Kbb + (size_t)(j0 + row) * 64 + c8);
            *(s16x8*)&Vl[row][c8] = *(const s16x8*)(Vbb + (size_t)row * JP + j0 + c8);
        }
        __syncthreads();

        // S^T = K Q^T : lane holds col=lr=q-row, rows j = j0 + jf*16 + lg*4 + r
        f32x4 sf[4] = {};
#pragma unroll
        for (int kk = 0; kk < 2; kk++)
#pragma unroll
            for (int jf = 0; jf < 4; jf++) {
                s16x8 kf = *(const s16x8*)&Kl[jf * 16 + lr][kk * 32 + lg * 8];
                sf[jf] = __builtin_amdgcn_mfma_f32_16x16x32_bf16(kf, qf[kk], sf[jf], 0, 0, 0);
            }
        if (j0 + 64 > Jv) {   // mask padded tokens (last tile only; uniform branch)
#pragma unroll
            for (int jf = 0; jf < 4; jf++)
#pragma unroll
                for (int r = 0; r < 4; r++)
                    if (j0 + jf * 16 + lg * 4 + r >= Jv) sf[jf][r] = -1e30f;
        }

        // online softmax: row = q = n0+lr per lane; reduce in-lane + across lg groups
        float pm = -1e30f;
#pragma unroll
        for (int jf = 0; jf < 4; jf++)
#pragma unroll
            for (int r = 0; r < 4; r++) pm = fmaxf(pm, sf[jf][r]);
        pm = fmaxf(pm, __shfl_xor(pm, 16, 64));
        pm = fmaxf(pm, __shfl_xor(pm, 32, 64));
        float mnew = fmaxf(Mv, pm);
        float sum = 0.0f;
#pragma unroll
        for (int jf = 0; jf < 4; jf++)
#pragma unroll
            for (int r = 0; r < 4; r++) {
                float p = __expf(sf[jf][r] - mnew);
                sf[jf][r] = p;
                sum += p;
            }
        sum += __shfl_xor(sum, 16, 64);
        sum += __shfl_xor(sum, 32, 64);
        float alpha = __expf(Mv - mnew);
        Lv = Lv * alpha + sum;
        Mv = mnew;
#pragma unroll
        for (int df = 0; df < 4; df++)
#pragma unroll
            for (int r = 0; r < 4; r++) O[df][r] *= alpha;

        // pack P^T -> per-wave LDS: lane writes its 8 u32 contiguously
        unsigned pk[8];
#pragma unroll
        for (int jf = 0; jf < 4; jf++) {
            pk[jf * 2 + 0] = pack_bf(sf[jf][0], sf[jf][1]);
            pk[jf * 2 + 1] = pack_bf(sf[jf][2], sf[jf][3]);
        }
        *(uint2*)(pwr + 0) = make_uint2(pk[0], pk[1]);
        *(uint2*)(pwr + 2) = make_uint2(pk[2], pk[3]);
        *(uint2*)(pwr + 4) = make_uint2(pk[4], pk[5]);
        *(uint2*)(pwr + 6) = make_uint2(pk[6], pk[7]);

        // O^T += V^T P^T : A = Vl rows d, B = P^T (col=lr=q, k=j)
#pragma unroll
        for (int kk = 0; kk < 2; kk++) {
            uint2 a2 = *(const uint2*)(prd + pbase + kk * 4);
            uint2 c2 = *(const uint2*)(prd + pbase + kk * 4 + 8);
            union { uint2 p[2]; s16x8 v; } pu;
            pu.p[0] = a2; pu.p[1] = c2;
            s16x8 pf = pu.v;
#pragma unroll
            for (int df = 0; df < 4; df++) {
                s16x8 vf = *(const s16x8*)&Vl[df * 16 + lr][kk * 32 + lg * 8];
                O[df] = __builtin_amdgcn_mfma_f32_16x16x32_bf16(vf, pf, O[df], 0, 0, 0);
            }
        }
    }

    // epilogue: normalize, transpose via (dead) Kl, write coalesced
    __syncthreads();   // all waves done reading Kl
    float rl = 1.0f / Lv;
    unsigned short* Ol = &Kl[wid * 16][0];     // per-wave 16 x 72 slab
#pragma unroll
    for (int df = 0; df < 4; df++)
#pragma unroll
        for (int r = 0; r < 4; r++)
            Ol[lr * 72 + df * 16 + lg * 4 + r] = f2bf(O[df][r] * rl);
    int orow = lane >> 2, part = lane & 3;
    const s16x8* src = (const s16x8*)&Kl[wid * 16 + orow][part * 16];
    s16x8 o0 = src[0], o1 = src[1];
    unsigned short* gdst = aout + (size_t)(b * Nn + n0 + orow) * 1024 + h * 64 + part * 16;
    *(s16x8*)gdst = o0;
    *((s16x8*)gdst + 1) = o1;
}

// ---------------- launch ----------------
extern "C" void kernel_launch(void* const* d_in, const int* in_sizes, int n_in,
                              void* d_out, int out_size, void* d_ws, size_t ws_size,
                              hipStream_t stream) {
    const float* x    = (const float*)d_in[0];
    const float* ctx  = (const float*)d_in[1];
    const float* g1   = (const float*)d_in[2];
    const float* Wq   = (const float*)d_in[3];
    const float* Wkv  = (const float*)d_in[4];
    const float* nkv  = (const float*)d_in[5];
    const float* ctxg = (const float*)d_in[6];
    const float* ctxb = (const float*)d_in[7];
    const float* Wc   = (const float*)d_in[8];
    const float* bc   = (const float*)d_in[9];
    const float* Wout = (const float*)d_in[10];
    const float* g2   = (const float*)d_in[11];
    float* out = (float*)d_out;

    char* w = (char*)d_ws;
    unsigned short* h_    = (unsigned short*)w; w += (size_t)4096 * 1024 * 2;
    unsigned short* ch    = (unsigned short*)w; w += (size_t)512 * 1024 * 2;
    unsigned short* WqkvT = (unsigned short*)w; w += (size_t)1152 * 1024 * 2;
    unsigned short* WcT   = (unsigned short*)w; w += (size_t)128 * 1024 * 2;
    unsigned short* WoutT = (unsigned short*)w; w += (size_t)1024 * 1024 * 2;
    unsigned short* qkv   = (unsigned short*)w; w += (size_t)4096 * 1152 * 2;
    unsigned short* ckv   = (unsigned short*)w; w += (size_t)512 * 128 * 2;
    unsigned short* Kb    = (unsigned short*)w; w += (size_t)Bb * JP * 64 * 2;
    unsigned short* Vt    = (unsigned short*)w; w += (size_t)Bb * 64 * JP * 2;
    unsigned short* aout  = (unsigned short*)w; w += (size_t)4096 * 1024 * 2;
    float* preout         = (float*)w;          w += (size_t)4096 * 1024 * 4;

    const float qscale = 0.125f;  // DH^-0.5

    // weight transposes (f32 -> bf16, B^T layout)
    k_transpose<<<dim3(32, 32), 256, 0, stream>>>(Wq,   WqkvT,                 1024, 1024, qscale);
    k_transpose<<<dim3(4,  32), 256, 0, stream>>>(Wkv,  WqkvT + 1024 * 1024,   1024, 128,  1.0f);
    k_transpose<<<dim3(4,  32), 256, 0, stream>>>(Wc,   WcT,                   1024, 128,  1.0f);
    k_transpose<<<dim3(32, 32), 256, 0, stream>>>(Wout, WoutT,                 1024, 1024, 1.0f);

    // layernorms
    k_ln<false, true><<<4096, 256, 0, stream>>>(x,   g1,   nullptr, h_, 1e-5f);
    k_ln<true,  true><<<512,  256, 0, stream>>>(ctx, ctxg, ctxb,    ch, 1e-6f);

    // projections
    k_gemm_bt<1><<<dim3(9, 32), 256, 0, stream>>>(h_, WqkvT, qkv, 4096, 1152, 1024);
    k_gemm_bt<1><<<dim3(1, 4),  256, 0, stream>>>(ch, WcT,   ckv, 512,  128,  1024);

    // build K (row-major) and V^T
    k_assemble_kv<<<(Bb * JP * 64) / 256, 256, 0, stream>>>(qkv, ckv, nkv, bc, Kb, Vt);

    // attention
    k_attn<<<Bb * Hh * (Nn / 64), 256, 0, stream>>>(qkv, Kb, Vt, aout);

    // output projection + final LN
    k_gemm_bt<0><<<dim3(8, 32), 256, 0, stream>>>(aout, WoutT, preout, 4096, 1024, 1024);
    k_ln<false, false><<<4096, 256, 0, stream>>>(preout, g2, nullptr, out, 1e-5f);
}

// Round 3
// 172.528 us; speedup vs baseline: 1.6731x; 1.1042x over previous
//
#include <hip/hip_runtime.h>

typedef __attribute__((ext_vector_type(4))) float  f32x4;
typedef __attribute__((ext_vector_type(8))) short  s16x8;

#define DEVI __device__ __forceinline__

// ---------------- constants ----------------
constexpr int Bb   = 2;
constexpr int Nn   = 2048;
constexpr int Hh   = 16;
constexpr int DHc  = 64;
constexpr int CTXN = 256;
constexpr int Jv   = Nn + 1 + CTXN;   // 2305 valid kv tokens
constexpr int JP   = 2368;            // padded to 37*64
constexpr int QKVN = Hh*DHc + 2*DHc;  // 1152

// ---------------- helpers ----------------
DEVI unsigned short f2bf(float f) {
    union { float f; unsigned u; } v; v.f = f;
    unsigned r = v.u + 0x7fffu + ((v.u >> 16) & 1u);
    return (unsigned short)(r >> 16);
}
DEVI float bf2f(unsigned short h) {
    union { unsigned u; float f; } v; v.u = ((unsigned)h) << 16;
    return v.f;
}
DEVI unsigned cvt_pk_bf(float lo, float hi) {   // dst.lo=bf16(lo), dst.hi=bf16(hi)
    unsigned r;
    asm("v_cvt_pk_bf16_f32 %0, %1, %2" : "=v"(r) : "v"(lo), "v"(hi));
    return r;
}
DEVI float exp2v(float x) {                      // v_exp_f32 = 2^x
    float r;
    asm("v_exp_f32 %0, %1" : "=v"(r) : "v"(x));
    return r;
}
// async global->LDS, 16B per lane; LDS dest = uniform base + lane*16 (linear)
DEVI void gl_lds16(const void* g, void* l) {
    __builtin_amdgcn_global_load_lds(
        (__attribute__((address_space(1))) void*)g,
        (__attribute__((address_space(3))) void*)l,
        16, 0, 0);
}

// ---------------- transpose f32 [R][C] -> bf16 [C][R], with scale ----------------
__global__ __launch_bounds__(256) void k_transpose(const float* __restrict__ in,
                                                   unsigned short* __restrict__ out,
                                                   int R, int C, float scale) {
    __shared__ float tile[32][33];
    int tx = threadIdx.x & 31, ty = threadIdx.x >> 5;   // 32 x 8
    int r0 = blockIdx.y * 32, c0 = blockIdx.x * 32;
#pragma unroll
    for (int i = 0; i < 32; i += 8)
        tile[ty + i][tx] = in[(size_t)(r0 + ty + i) * C + c0 + tx];
    __syncthreads();
#pragma unroll
    for (int i = 0; i < 32; i += 8)
        out[(size_t)(c0 + ty + i) * R + r0 + tx] = f2bf(tile[tx][ty + i] * scale);
}

// ---------------- LayerNorm, 1024 cols, 256 threads/row ----------------
template<bool BETA, bool OUT_BF16>
__global__ __launch_bounds__(256) void k_ln(const float* __restrict__ in,
                                            const float* __restrict__ g,
                                            const float* __restrict__ b,
                                            void* __restrict__ out, float eps) {
    int row = blockIdx.x, tid = threadIdx.x;
    const float* rp = in + (size_t)row * 1024;
    f32x4 v = *(const f32x4*)(rp + tid * 4);
    float s = v.x + v.y + v.z + v.w;
    float q = v.x * v.x + v.y * v.y + v.z * v.z + v.w * v.w;
#pragma unroll
    for (int m = 32; m; m >>= 1) { s += __shfl_down(s, m, 64); q += __shfl_down(q, m, 64); }
    __shared__ float ss[4], sq[4];
    int wid = tid >> 6, lane = tid & 63;
    if (lane == 0) { ss[wid] = s; sq[wid] = q; }
    __syncthreads();
    s = ss[0] + ss[1] + ss[2] + ss[3];
    q = sq[0] + sq[1] + sq[2] + sq[3];
    float mean = s * (1.0f / 1024.0f);
    float var  = q * (1.0f / 1024.0f) - mean * mean;
    float rstd = rsqrtf(var + eps);
    f32x4 gg = *(const f32x4*)(g + tid * 4);
    f32x4 r;
#pragma unroll
    for (int e = 0; e < 4; e++) r[e] = (v[e] - mean) * rstd * gg[e];
    if (BETA) {
        f32x4 bb = *(const f32x4*)(b + tid * 4);
#pragma unroll
        for (int e = 0; e < 4; e++) r[e] += bb[e];
    }
    if (OUT_BF16) {
        uint2 o = make_uint2(cvt_pk_bf(r[0], r[1]), cvt_pk_bf(r[2], r[3]));
        *(uint2*)((unsigned short*)out + (size_t)row * 1024 + tid * 4) = o;
    } else {
        *(f32x4*)((float*)out + (size_t)row * 1024 + tid * 4) = r;
    }
}

// ---------------- GEMM: C[M][N] = A[M][K](bf16) * BT[N][K](bf16)^T ----------------
// 128x128 tile, BK=64, 4 waves (2x2), global_load_lds staging w/ XOR-swizzled source.
// LDS tile linear [128][64]; logical 16B slot s of row r lives at phys slot s^(r&7).
template<int OUT_BF16>
__global__ __launch_bounds__(256) void k_gemm_bt(const unsigned short* __restrict__ A,
                                                 const unsigned short* __restrict__ BT,
                                                 void* __restrict__ C,
                                                 int M, int N, int K) {
    __shared__ unsigned short Al[128 * 64];
    __shared__ unsigned short Bl[128 * 64];
    int tid = threadIdx.x;
    int bn = blockIdx.x, bm = blockIdx.y;
    int wid = tid >> 6, lane = tid & 63;
    int wm = wid >> 1, wn = wid & 1;
    int lr = lane & 15, lg = lane >> 4;
    int r8 = lane >> 3;                 // 0..7 (row within 8-row block)
    int sl = (lane & 7) ^ r8;           // pre-swizzled source slot

    // staging bases: wave w covers rows w*32 + i*8 + r8
    const unsigned short* Ag = A  + (size_t)(bm * 128 + wid * 32 + r8) * K + sl * 8;
    const unsigned short* Bg = BT + (size_t)(bn * 128 + wid * 32 + r8) * K + sl * 8;
    unsigned short* Ad = &Al[wid * 32 * 64];
    unsigned short* Bd = &Bl[wid * 32 * 64];

    f32x4 acc[4][4] = {};
    for (int k0 = 0; k0 < K; k0 += 64) {
        __syncthreads();                 // prev MFMA reads done
#pragma unroll
        for (int i = 0; i < 4; i++) {
            gl_lds16(Ag + (size_t)i * 8 * K + k0, Ad + i * 512);
            gl_lds16(Bg + (size_t)i * 8 * K + k0, Bd + i * 512);
        }
        __syncthreads();                 // drains vmcnt
#pragma unroll
        for (int kk = 0; kk < 2; kk++) {
            int co = ((kk * 4 + lg) ^ (lr & 7)) * 8;
            s16x8 af[4], bf[4];
#pragma unroll
            for (int mi = 0; mi < 4; mi++)
                af[mi] = *(const s16x8*)&Al[(wm * 64 + mi * 16 + lr) * 64 + co];
#pragma unroll
            for (int ni = 0; ni < 4; ni++)
                bf[ni] = *(const s16x8*)&Bl[(wn * 64 + ni * 16 + lr) * 64 + co];
#pragma unroll
            for (int mi = 0; mi < 4; mi++)
#pragma unroll
                for (int ni = 0; ni < 4; ni++)
                    acc[mi][ni] = __builtin_amdgcn_mfma_f32_16x16x32_bf16(af[mi], bf[ni], acc[mi][ni], 0, 0, 0);
        }
    }
#pragma unroll
    for (int mi = 0; mi < 4; mi++)
#pragma unroll
        for (int r = 0; r < 4; r++) {
            int row = bm * 128 + wm * 64 + mi * 16 + lg * 4 + r;
#pragma unroll
            for (int ni = 0; ni < 4; ni++) {
                int col = bn * 128 + wn * 64 + ni * 16 + lr;
                float val = acc[mi][ni][r];
                if (OUT_BF16)
                    ((unsigned short*)C)[(size_t)row * N + col] = f2bf(val);
                else
                    ((float*)C)[(size_t)row * N + col] = val;
            }
        }
}

// ---------------- assemble K (row-major [b][j][d]) and V^T ([b][d][JP]) ----------------
__global__ __launch_bounds__(256) void k_assemble_kv(const unsigned short* __restrict__ qkv,
                                                     const unsigned short* __restrict__ ckv,
                                                     const float* __restrict__ nkv,
                                                     const float* __restrict__ bc,
                                                     unsigned short* __restrict__ Kb,
                                                     unsigned short* __restrict__ Vt) {
    int idx = blockIdx.x * 256 + threadIdx.x;   // Bb*JP*64 total
    int d = idx & 63;
    int j = (idx >> 6) % JP;
    int b = idx / (64 * JP);
    float kv, vv;
    if (j < Nn) {
        const unsigned short* r = qkv + (size_t)(b * Nn + j) * QKVN + Hh * DHc;
        kv = bf2f(r[d]); vv = bf2f(r[64 + d]);
    } else if (j == Nn) {
        kv = nkv[d]; vv = nkv[64 + d];
    } else if (j < Jv) {
        const unsigned short* r = ckv + (size_t)(b * CTXN + (j - Nn - 1)) * 128;
        kv = bf2f(r[d]) + bc[d]; vv = bf2f(r[64 + d]) + bc[64 + d];
    } else {
        kv = 0.0f; vv = 0.0f;
    }
    Kb[((size_t)b * JP + j) * 64 + d] = f2bf(kv);
    Vt[((size_t)b * 64 + d) * JP + j] = f2bf(vv);
}

// ---------------- flash attention (swapped-operand, exp2-domain, defer-max) ----------------
// grid: b(2) x h(16) x qtile(32).  block = 256 = 4 waves; wave owns 16 q-rows (q = n0 + lr).
// Kl/Vl: linear [64][64] bf16, staged via global_load_lds with XOR-swizzled source.
__global__ __launch_bounds__(256) void k_attn(const unsigned short* __restrict__ qkv,
                                              const unsigned short* __restrict__ Kb,
                                              const unsigned short* __restrict__ Vt,
                                              unsigned short* __restrict__ aout) {
    __shared__ unsigned short Kl[64 * 64];    // K rows [j][d]
    __shared__ unsigned short Vl[64 * 64];    // V^T rows [d][j]
    __shared__ unsigned       Pp[4][16][34];  // per-wave packed P^T
    __shared__ unsigned short Ot[4][16][72];  // epilogue transpose slab

    int bid = blockIdx.x;
    int qt = bid & 31, h = (bid >> 5) & 15, b = bid >> 9;
    int tid = threadIdx.x, wid = tid >> 6, lane = tid & 63;
    int lr = lane & 15, lg = lane >> 4;
    int n0 = qt * 64 + wid * 16;
    int r8 = lane >> 3;
    int sl = (lane & 7) ^ r8;

    // Q fragments (B-operand): col=lr -> q row n0+lr, k = kk*32 + lg*8 + e
    s16x8 qf[2];
#pragma unroll
    for (int kk = 0; kk < 2; kk++)
        qf[kk] = *(const s16x8*)(qkv + (size_t)(b * Nn + n0 + lr) * QKVN + h * 64 + kk * 32 + lg * 8);

    f32x4 O[4] = {};        // O^T frags: col=lr=q, row d = df*16 + lg*4 + r
    float Mv = -1e30f, Lv = 0.0f;

    // staging bases: wave w covers rows w*16 + i*8 + r8 (i=0,1)
    const unsigned short* Kg = Kb + ((size_t)b * JP + wid * 16 + r8) * 64 + sl * 8;
    const unsigned short* Vg = Vt + ((size_t)b * 64 + wid * 16 + r8) * JP + sl * 8;
    unsigned short* Kd = &Kl[wid * 16 * 64];
    unsigned short* Vd = &Vl[wid * 16 * 64];

    int pbase = ((2 * lg) & 3) * 8 + (lg >> 1) * 2;
    unsigned* pwr = &Pp[wid][lr][lg * 8];
    const unsigned* prd = &Pp[wid][lr][0];

    for (int j0 = 0; j0 < JP; j0 += 64) {
        __syncthreads();   // prev-iter LDS reads done
#pragma unroll
        for (int i = 0; i < 2; i++) {
            gl_lds16(Kg + ((size_t)j0 + i * 8) * 64, Kd + i * 512);
            gl_lds16(Vg + (size_t)i * 8 * JP + j0,   Vd + i * 512);
        }
        __syncthreads();   // drains vmcnt

        // S^T = K Q^T : lane holds col=lr=q-row, rows j = j0 + jf*16 + lg*4 + r  (log2 units)
        f32x4 sf[4] = {};
#pragma unroll
        for (int kk = 0; kk < 2; kk++) {
            int co = ((kk * 4 + lg) ^ (lr & 7)) * 8;
#pragma unroll
            for (int jf = 0; jf < 4; jf++) {
                s16x8 kf = *(const s16x8*)&Kl[(jf * 16 + lr) * 64 + co];
                sf[jf] = __builtin_amdgcn_mfma_f32_16x16x32_bf16(kf, qf[kk], sf[jf], 0, 0, 0);
            }
        }
        if (j0 + 64 > Jv) {   // mask padded tokens (last tile only; uniform branch)
#pragma unroll
            for (int jf = 0; jf < 4; jf++)
#pragma unroll
                for (int r = 0; r < 4; r++)
                    if (j0 + jf * 16 + lg * 4 + r >= Jv) sf[jf][r] = -1e30f;
        }

        // online softmax, row = q = n0+lr per lane
        float pm = fmaxf(fmaxf(fmaxf(sf[0][0], sf[0][1]), fmaxf(sf[0][2], sf[0][3])),
                         fmaxf(fmaxf(sf[1][0], sf[1][1]), fmaxf(sf[1][2], sf[1][3])));
        pm = fmaxf(pm, fmaxf(fmaxf(fmaxf(sf[2][0], sf[2][1]), fmaxf(sf[2][2], sf[2][3])),
                             fmaxf(fmaxf(sf[3][0], sf[3][1]), fmaxf(sf[3][2], sf[3][3]))));
        pm = fmaxf(pm, __shfl_xor(pm, 16, 64));
        pm = fmaxf(pm, __shfl_xor(pm, 32, 64));
        if (!__all(pm - Mv <= 8.0f)) {        // defer-max: rescale only on real growth
            float mnew = fmaxf(Mv, pm);
            float alpha = exp2v(Mv - mnew);
            Lv *= alpha;
#pragma unroll
            for (int df = 0; df < 4; df++)
#pragma unroll
                for (int r = 0; r < 4; r++) O[df][r] *= alpha;
            Mv = mnew;
        }
        float sum = 0.0f;
#pragma unroll
        for (int jf = 0; jf < 4; jf++)
#pragma unroll
            for (int r = 0; r < 4; r++) {
                float p = exp2v(sf[jf][r] - Mv);
                sf[jf][r] = p;
                sum += p;
            }
        sum += __shfl_xor(sum, 16, 64);
        sum += __shfl_xor(sum, 32, 64);
        Lv += sum;

        // pack P^T -> per-wave LDS (v_cvt_pk_bf16_f32), lane writes 8 u32 contiguous
        *(uint2*)(pwr + 0) = make_uint2(cvt_pk_bf(sf[0][0], sf[0][1]), cvt_pk_bf(sf[0][2], sf[0][3]));
        *(uint2*)(pwr + 2) = make_uint2(cvt_pk_bf(sf[1][0], sf[1][1]), cvt_pk_bf(sf[1][2], sf[1][3]));
        *(uint2*)(pwr + 4) = make_uint2(cvt_pk_bf(sf[2][0], sf[2][1]), cvt_pk_bf(sf[2][2], sf[2][3]));
        *(uint2*)(pwr + 6) = make_uint2(cvt_pk_bf(sf[3][0], sf[3][1]), cvt_pk_bf(sf[3][2], sf[3][3]));

        // O^T += V^T P^T : A = Vl rows d, B = P^T (col=lr=q, k=j)
#pragma unroll
        for (int kk = 0; kk < 2; kk++) {
            uint2 a2 = *(const uint2*)(prd + pbase + kk * 4);
            uint2 c2 = *(const uint2*)(prd + pbase + kk * 4 + 8);
            union { uint2 p[2]; s16x8 v; } pu;
            pu.p[0] = a2; pu.p[1] = c2;
            s16x8 pf = pu.v;
            int co = ((kk * 4 + lg) ^ (lr & 7)) * 8;
#pragma unroll
            for (int df = 0; df < 4; df++) {
                s16x8 vf = *(const s16x8*)&Vl[(df * 16 + lr) * 64 + co];
                O[df] = __builtin_amdgcn_mfma_f32_16x16x32_bf16(vf, pf, O[df], 0, 0, 0);
            }
        }
    }

    // epilogue: normalize, transpose via per-wave Ot slab, write coalesced
    float rl = 1.0f / Lv;
    unsigned short* op = &Ot[wid][lr][0];
#pragma unroll
    for (int df = 0; df < 4; df++) {
        uint2 w2 = make_uint2(cvt_pk_bf(O[df][0] * rl, O[df][1] * rl),
                              cvt_pk_bf(O[df][2] * rl, O[df][3] * rl));
        *(uint2*)&op[df * 16 + lg * 4] = w2;
    }
    int orow = lane >> 2, part = lane & 3;
    const s16x8* src = (const s16x8*)&Ot[wid][orow][part * 16];
    s16x8 o0 = src[0], o1 = src[1];
    unsigned short* gdst = aout + (size_t)(b * Nn + n0 + orow) * 1024 + h * 64 + part * 16;
    *(s16x8*)gdst = o0;
    *((s16x8*)gdst + 1) = o1;
}

// ---------------- launch ----------------
extern "C" void kernel_launch(void* const* d_in, const int* in_sizes, int n_in,
                              void* d_out, int out_size, void* d_ws, size_t ws_size,
                              hipStream_t stream) {
    const float* x    = (const float*)d_in[0];
    const float* ctx  = (const float*)d_in[1];
    const float* g1   = (const float*)d_in[2];
    const float* Wq   = (const float*)d_in[3];
    const float* Wkv  = (const float*)d_in[4];
    const float* nkv  = (const float*)d_in[5];
    const float* ctxg = (const float*)d_in[6];
    const float* ctxb = (const float*)d_in[7];
    const float* Wc   = (const float*)d_in[8];
    const float* bc   = (const float*)d_in[9];
    const float* Wout = (const float*)d_in[10];
    const float* g2   = (const float*)d_in[11];
    float* out = (float*)d_out;

    char* w = (char*)d_ws;
    unsigned short* h_    = (unsigned short*)w; w += (size_t)4096 * 1024 * 2;
    unsigned short* ch    = (unsigned short*)w; w += (size_t)512 * 1024 * 2;
    unsigned short* WqkvT = (unsigned short*)w; w += (size_t)1152 * 1024 * 2;
    unsigned short* WcT   = (unsigned short*)w; w += (size_t)128 * 1024 * 2;
    unsigned short* WoutT = (unsigned short*)w; w += (size_t)1024 * 1024 * 2;
    unsigned short* qkv   = (unsigned short*)w; w += (size_t)4096 * 1152 * 2;
    unsigned short* ckv   = (unsigned short*)w; w += (size_t)512 * 128 * 2;
    unsigned short* Kb    = (unsigned short*)w; w += (size_t)Bb * JP * 64 * 2;
    unsigned short* Vt    = (unsigned short*)w; w += (size_t)Bb * 64 * JP * 2;
    unsigned short* aout  = (unsigned short*)w; w += (size_t)4096 * 1024 * 2;
    float* preout         = (float*)w;          w += (size_t)4096 * 1024 * 4;

    // fold softmax scale AND log2(e) into Wq so QK^T lands in exp2 domain
    const float qscale = 0.125f * 1.4426950408889634f;

    // weight transposes (f32 -> bf16, B^T layout)
    k_transpose<<<dim3(32, 32), 256, 0, stream>>>(Wq,   WqkvT,                 1024, 1024, qscale);
    k_transpose<<<dim3(4,  32), 256, 0, stream>>>(Wkv,  WqkvT + 1024 * 1024,   1024, 128,  1.0f);
    k_transpose<<<dim3(4,  32), 256, 0, stream>>>(Wc,   WcT,                   1024, 128,  1.0f);
    k_transpose<<<dim3(32, 32), 256, 0, stream>>>(Wout, WoutT,                 1024, 1024, 1.0f);

    // layernorms
    k_ln<false, true><<<4096, 256, 0, stream>>>(x,   g1,   nullptr, h_, 1e-5f);
    k_ln<true,  true><<<512,  256, 0, stream>>>(ctx, ctxg, ctxb,    ch, 1e-6f);

    // projections
    k_gemm_bt<1><<<dim3(9, 32), 256, 0, stream>>>(h_, WqkvT, qkv, 4096, 1152, 1024);
    k_gemm_bt<1><<<dim3(1, 4),  256, 0, stream>>>(ch, WcT,   ckv, 512,  128,  1024);

    // build K (row-major) and V^T
    k_assemble_kv<<<(Bb * JP * 64) / 256, 256, 0, stream>>>(qkv, ckv, nkv, bc, Kb, Vt);

    // attention
    k_attn<<<Bb * Hh * (Nn / 64), 256, 0, stream>>>(qkv, Kb, Vt, aout);

    // output projection + final LN
    k_gemm_bt<0><<<dim3(8, 32), 256, 0, stream>>>(aout, WoutT, preout, 4096, 1024, 1024);
    k_ln<false, false><<<4096, 256, 0, stream>>>(preout, g2, nullptr, out, 1e-5f);
}

// Round 5
// 164.943 us; speedup vs baseline: 1.7500x; 1.0460x over previous
//
#include <hip/hip_runtime.h>

typedef __attribute__((ext_vector_type(4))) float  f32x4;
typedef __attribute__((ext_vector_type(8))) short  s16x8;

#define DEVI __device__ __forceinline__

// ---------------- constants ----------------
constexpr int Bb   = 2;
constexpr int Nn   = 2048;
constexpr int Hh   = 16;
constexpr int DHc  = 64;
constexpr int CTXN = 256;
constexpr int Jv   = Nn + 1 + CTXN;   // 2305 valid kv tokens
constexpr int JP   = 2368;            // padded to 37*64
constexpr int QKVN = Hh*DHc + 2*DHc;  // 1152

// ---------------- helpers ----------------
DEVI unsigned short f2bf(float f) {
    union { float f; unsigned u; } v; v.f = f;
    unsigned r = v.u + 0x7fffu + ((v.u >> 16) & 1u);
    return (unsigned short)(r >> 16);
}
DEVI float bf2f(unsigned short h) {
    union { unsigned u; float f; } v; v.u = ((unsigned)h) << 16;
    return v.f;
}
DEVI unsigned cvt_pk_bf(float lo, float hi) {   // dst.lo=bf16(lo), dst.hi=bf16(hi)
    unsigned r;
    asm("v_cvt_pk_bf16_f32 %0, %1, %2" : "=v"(r) : "v"(lo), "v"(hi));
    return r;
}
DEVI float exp2v(float x) {                      // v_exp_f32 = 2^x
    float r;
    asm("v_exp_f32 %0, %1" : "=v"(r) : "v"(x));
    return r;
}
// async global->LDS, 16B per lane; LDS dest = uniform base + lane*16 (linear)
DEVI void gl_lds16(const void* g, void* l) {
    __builtin_amdgcn_global_load_lds(
        (__attribute__((address_space(1))) void*)g,
        (__attribute__((address_space(3))) void*)l,
        16, 0, 0);
}

// ---------------- all weight transposes in one launch ----------------
// f32 [1024][C] -> bf16 [C][1024] (B^T layout), optional scale
__global__ __launch_bounds__(256) void k_transpose_all(const float* __restrict__ Wq,
                                                       const float* __restrict__ Wkv,
                                                       const float* __restrict__ Wc,
                                                       const float* __restrict__ Wout,
                                                       unsigned short* __restrict__ WqkvT,
                                                       unsigned short* __restrict__ WcT,
                                                       unsigned short* __restrict__ WoutT,
                                                       float qscale) {
    __shared__ float tile[32][33];
    int bx = blockIdx.x;
    const float* in; unsigned short* out; int C; float scale; int cb;
    if (bx < 32)      { in = Wq;   out = WqkvT;               C = 1024; scale = qscale; cb = bx; }
    else if (bx < 36) { in = Wkv;  out = WqkvT + 1024 * 1024; C = 128;  scale = 1.0f;  cb = bx - 32; }
    else if (bx < 40) { in = Wc;   out = WcT;                 C = 128;  scale = 1.0f;  cb = bx - 36; }
    else              { in = Wout; out = WoutT;               C = 1024; scale = 1.0f;  cb = bx - 40; }
    int tx = threadIdx.x & 31, ty = threadIdx.x >> 5;   // 32 x 8
    int r0 = blockIdx.y * 32, c0 = cb * 32;
#pragma unroll
    for (int i = 0; i < 32; i += 8)
        tile[ty + i][tx] = in[(size_t)(r0 + ty + i) * C + c0 + tx];
    __syncthreads();
#pragma unroll
    for (int i = 0; i < 32; i += 8)
        out[(size_t)(c0 + ty + i) * 1024 + r0 + tx] = f2bf(tile[tx][ty + i] * scale);
}

// ---------------- merged input LayerNorms (x rows 0..4095, ctx rows 4096..4607) ----------------
__global__ __launch_bounds__(256) void k_ln_in(const float* __restrict__ x,
                                               const float* __restrict__ ctx,
                                               const float* __restrict__ g1,
                                               const float* __restrict__ cg,
                                               const float* __restrict__ cb,
                                               unsigned short* __restrict__ h,
                                               unsigned short* __restrict__ ch) {
    int row = blockIdx.x, tid = threadIdx.x;
    bool isx = row < 4096;
    const float* rp = isx ? x + (size_t)row * 1024 : ctx + (size_t)(row - 4096) * 1024;
    const float* g  = isx ? g1 : cg;
    float eps = isx ? 1e-5f : 1e-6f;
    unsigned short* o = isx ? h + (size_t)row * 1024 : ch + (size_t)(row - 4096) * 1024;

    f32x4 v = *(const f32x4*)(rp + tid * 4);
    float s = v.x + v.y + v.z + v.w;
    float q = v.x * v.x + v.y * v.y + v.z * v.z + v.w * v.w;
#pragma unroll
    for (int m = 32; m; m >>= 1) { s += __shfl_down(s, m, 64); q += __shfl_down(q, m, 64); }
    __shared__ float ss[4], sq[4];
    int wid = tid >> 6, lane = tid & 63;
    if (lane == 0) { ss[wid] = s; sq[wid] = q; }
    __syncthreads();
    s = ss[0] + ss[1] + ss[2] + ss[3];
    q = sq[0] + sq[1] + sq[2] + sq[3];
    float mean = s * (1.0f / 1024.0f);
    float var  = q * (1.0f / 1024.0f) - mean * mean;
    float rstd = rsqrtf(var + eps);
    f32x4 gg = *(const f32x4*)(g + tid * 4);
    f32x4 r;
#pragma unroll
    for (int e = 0; e < 4; e++) r[e] = (v[e] - mean) * rstd * gg[e];
    if (!isx) {
        f32x4 bb = *(const f32x4*)(cb + tid * 4);
#pragma unroll
        for (int e = 0; e < 4; e++) r[e] += bb[e];
    }
    uint2 ov = make_uint2(cvt_pk_bf(r[0], r[1]), cvt_pk_bf(r[2], r[3]));
    *(uint2*)(o + tid * 4) = ov;
}

// ---------------- final LayerNorm (f32 out) ----------------
__global__ __launch_bounds__(256) void k_ln_out(const float* __restrict__ in,
                                                const float* __restrict__ g,
                                                float* __restrict__ out) {
    int row = blockIdx.x, tid = threadIdx.x;
    const float* rp = in + (size_t)row * 1024;
    f32x4 v = *(const f32x4*)(rp + tid * 4);
    float s = v.x + v.y + v.z + v.w;
    float q = v.x * v.x + v.y * v.y + v.z * v.z + v.w * v.w;
#pragma unroll
    for (int m = 32; m; m >>= 1) { s += __shfl_down(s, m, 64); q += __shfl_down(q, m, 64); }
    __shared__ float ss[4], sq[4];
    int wid = tid >> 6, lane = tid & 63;
    if (lane == 0) { ss[wid] = s; sq[wid] = q; }
    __syncthreads();
    s = ss[0] + ss[1] + ss[2] + ss[3];
    q = sq[0] + sq[1] + sq[2] + sq[3];
    float mean = s * (1.0f / 1024.0f);
    float var  = q * (1.0f / 1024.0f) - mean * mean;
    float rstd = rsqrtf(var + 1e-5f);
    f32x4 gg = *(const f32x4*)(g + tid * 4);
    f32x4 r;
#pragma unroll
    for (int e = 0; e < 4; e++) r[e] = (v[e] - mean) * rstd * gg[e];
    *(f32x4*)(out + (size_t)row * 1024 + tid * 4) = r;
}

// ---------------- GEMM: C[M][N] = A[M][K](bf16) * BT[N][K](bf16)^T ----------------
// 64x64 tile, BK=64, 4 waves (2x2, wave=32x32), double-buffered global_load_lds staging.
template<int OUT_BF16>
__global__ __launch_bounds__(256) void k_gemm_bt(const unsigned short* __restrict__ A,
                                                 const unsigned short* __restrict__ BT,
                                                 void* __restrict__ C,
                                                 int M, int N, int K) {
    __shared__ unsigned short SA[2][64 * 64];
    __shared__ unsigned short SB[2][64 * 64];
    int tid = threadIdx.x;
    int bn = blockIdx.x, bm = blockIdx.y;
    int wid = tid >> 6, lane = tid & 63;
    int wm = wid >> 1, wn = wid & 1;
    int lr = lane & 15, lg = lane >> 4;
    int r8 = lane >> 3;                 // 0..7
    int sl = (lane & 7) ^ r8;           // pre-swizzled source slot

    const unsigned short* Ag = A  + (size_t)(bm * 64 + wid * 16 + r8) * K + sl * 8;
    const unsigned short* Bg = BT + (size_t)(bn * 64 + wid * 16 + r8) * K + sl * 8;

    auto stage = [&](int k0, int buf) {
#pragma unroll
        for (int i = 0; i < 2; i++) {
            gl_lds16(Ag + (size_t)i * 8 * K + k0, &SA[buf][wid * 1024 + i * 512]);
            gl_lds16(Bg + (size_t)i * 8 * K + k0, &SB[buf][wid * 1024 + i * 512]);
        }
    };

    f32x4 acc[2][2] = {};
    int nk = K >> 6;
    stage(0, 0);
    __syncthreads();
    int cur = 0;
    for (int s = 0; s < nk; ++s) {
        if (s + 1 < nk) stage((s + 1) << 6, cur ^ 1);
        const unsigned short* Al = &SA[cur][0];
        const unsigned short* Bl = &SB[cur][0];
#pragma unroll
        for (int kk = 0; kk < 2; kk++) {
            int co = ((kk * 4 + lg) ^ (lr & 7)) * 8;
            s16x8 af[2], bf[2];
#pragma unroll
            for (int mi = 0; mi < 2; mi++)
                af[mi] = *(const s16x8*)&Al[(wm * 32 + mi * 16 + lr) * 64 + co];
#pragma unroll
            for (int ni = 0; ni < 2; ni++)
                bf[ni] = *(const s16x8*)&Bl[(wn * 32 + ni * 16 + lr) * 64 + co];
#pragma unroll
            for (int mi = 0; mi < 2; mi++)
#pragma unroll
                for (int ni = 0; ni < 2; ni++)
                    acc[mi][ni] = __builtin_amdgcn_mfma_f32_16x16x32_bf16(af[mi], bf[ni], acc[mi][ni], 0, 0, 0);
        }
        __syncthreads();
        cur ^= 1;
    }
#pragma unroll
    for (int mi = 0; mi < 2; mi++)
#pragma unroll
        for (int r = 0; r < 4; r++) {
            int row = bm * 64 + wm * 32 + mi * 16 + lg * 4 + r;
#pragma unroll
            for (int ni = 0; ni < 2; ni++) {
                int col = bn * 64 + wn * 32 + ni * 16 + lr;
                float val = acc[mi][ni][r];
                if (OUT_BF16)
                    ((unsigned short*)C)[(size_t)row * N + col] = f2bf(val);
                else
                    ((float*)C)[(size_t)row * N + col] = val;
            }
        }
}

// ---------------- assemble K (row-major [b][j][d]) and V^T ([b][d][JP]) ----------------
__global__ __launch_bounds__(256) void k_assemble_kv(const unsigned short* __restrict__ qkv,
                                                     const unsigned short* __restrict__ ckv,
                                                     const float* __restrict__ nkv,
                                                     const float* __restrict__ bc,
                                                     unsigned short* __restrict__ Kb,
                                                     unsigned short* __restrict__ Vt) {
    int idx = blockIdx.x * 256 + threadIdx.x;   // Bb*JP*64 total
    int d = idx & 63;
    int j = (idx >> 6) % JP;
    int b = idx / (64 * JP);
    float kv, vv;
    if (j < Nn) {
        const unsigned short* r = qkv + (size_t)(b * Nn + j) * QKVN + Hh * DHc;
        kv = bf2f(r[d]); vv = bf2f(r[64 + d]);
    } else if (j == Nn) {
        kv = nkv[d]; vv = nkv[64 + d];
    } else if (j < Jv) {
        const unsigned short* r = ckv + (size_t)(b * CTXN + (j - Nn - 1)) * 128;
        kv = bf2f(r[d]) + bc[d]; vv = bf2f(r[64 + d]) + bc[64 + d];
    } else {
        kv = 0.0f; vv = 0.0f;
    }
    Kb[((size_t)b * JP + j) * 64 + d] = f2bf(kv);
    Vt[((size_t)b * 64 + d) * JP + j] = f2bf(vv);
}

// ---------------- flash attention: dbuf prefetch, ones-row L, defer-max, exp2 domain --------
// grid: b(2) x h(16) x qtile(32).  block = 256 = 4 waves; wave owns 16 q-rows (q = n0 + lr).
__global__ __launch_bounds__(256) void k_attn(const unsigned short* __restrict__ qkv,
                                              const unsigned short* __restrict__ Kb,
                                              const unsigned short* __restrict__ Vt,
                                              unsigned short* __restrict__ aout) {
    __shared__ unsigned short KV[2][2][64 * 64];  // [buf][0=K rows j][1=V^T rows d]
    __shared__ unsigned       Pp[4][16][34];      // per-wave packed P^T

    int bid = blockIdx.x;
    int qt = bid & 31, h = (bid >> 5) & 15, b = bid >> 9;
    int tid = threadIdx.x, wid = tid >> 6, lane = tid & 63;
    int lr = lane & 15, lg = lane >> 4;
    int n0 = qt * 64 + wid * 16;
    int r8 = lane >> 3;
    int sl = (lane & 7) ^ r8;

    // Q fragments (B-operand): col=lr -> q row n0+lr, k = kk*32 + lg*8 + e
    s16x8 qf[2];
#pragma unroll
    for (int kk = 0; kk < 2; kk++)
        qf[kk] = *(const s16x8*)(qkv + (size_t)(b * Nn + n0 + lr) * QKVN + h * 64 + kk * 32 + lg * 8);

    // ones A-fragment: row 0 = 1.0, rows 1..15 = 0  (for L = colsum(P) via MFMA)
    s16x8 onesf;
    {
        short o = (lr == 0) ? (short)0x3F80 : (short)0;
#pragma unroll
        for (int e = 0; e < 8; e++) onesf[e] = o;
    }

    f32x4 O[4] = {};        // O^T frags: col=lr=q, row d = df*16 + lg*4 + r
    f32x4 O4 = {};          // L accumulator (row 0 = sum of P)
    float Mv = -1e30f;

    const unsigned short* Kg = Kb + ((size_t)b * JP + wid * 16 + r8) * 64 + sl * 8;
    const unsigned short* Vg = Vt + ((size_t)b * 64 + wid * 16 + r8) * JP + sl * 8;

    auto stage = [&](int t, int buf) {
#pragma unroll
        for (int i = 0; i < 2; i++) {
            gl_lds16(Kg + (size_t)t * 4096 + i * 512, &KV[buf][0][wid * 1024 + i * 512]);
            gl_lds16(Vg + (size_t)i * 8 * JP + t * 64, &KV[buf][1][wid * 1024 + i * 512]);
        }
    };

    int pbase = ((2 * lg) & 3) * 8 + (lg >> 1) * 2;
    unsigned* pwr = &Pp[wid][lr][lg * 8];
    const unsigned* prd = &Pp[wid][lr][0];

    stage(0, 0);
    __syncthreads();
    int cur = 0;
#pragma unroll 1
    for (int t = 0; t < 37; ++t) {
        if (t < 36) stage(t + 1, cur ^ 1);
        const unsigned short* Kl = &KV[cur][0][0];
        const unsigned short* Vl = &KV[cur][1][0];

        // S^T = K Q^T : lane holds col=lr=q-row, rows j = t*64 + jf*16 + lg*4 + r  (log2 units)
        f32x4 sf[4] = {};
        __builtin_amdgcn_s_setprio(1);
#pragma unroll
        for (int kk = 0; kk < 2; kk++) {
            int co = ((kk * 4 + lg) ^ (lr & 7)) * 8;
#pragma unroll
            for (int jf = 0; jf < 4; jf++) {
                s16x8 kf = *(const s16x8*)&Kl[(jf * 16 + lr) * 64 + co];
                sf[jf] = __builtin_amdgcn_mfma_f32_16x16x32_bf16(kf, qf[kk], sf[jf], 0, 0, 0);
            }
        }
        __builtin_amdgcn_s_setprio(0);
        if (t == 36) {   // mask padded tokens (uniform branch)
#pragma unroll
            for (int jf = 0; jf < 4; jf++)
#pragma unroll
                for (int r = 0; r < 4; r++)
                    if (36 * 64 + jf * 16 + lg * 4 + r >= Jv) sf[jf][r] = -1e30f;
        }

        // row max (3-ary groupings -> v_max3)
        float t0 = fmaxf(fmaxf(sf[0][0], sf[0][1]), sf[0][2]);
        float t1 = fmaxf(fmaxf(sf[0][3], sf[1][0]), sf[1][1]);
        float t2 = fmaxf(fmaxf(sf[1][2], sf[1][3]), sf[2][0]);
        float t3 = fmaxf(fmaxf(sf[2][1], sf[2][2]), sf[2][3]);
        float t4 = fmaxf(fmaxf(sf[3][0], sf[3][1]), sf[3][2]);
        float t5 = fmaxf(fmaxf(t0, t1), sf[3][3]);
        float pm = fmaxf(fmaxf(t2, t3), fmaxf(t4, t5));
        pm = fmaxf(pm, __shfl_xor(pm, 16, 64));
        pm = fmaxf(pm, __shfl_xor(pm, 32, 64));
        if (!__all(pm - Mv <= 8.0f)) {        // defer-max: rescale only on real growth
            float mnew = fmaxf(Mv, pm);
            float alpha = exp2v(Mv - mnew);
#pragma unroll
            for (int df = 0; df < 4; df++)
#pragma unroll
                for (int r = 0; r < 4; r++) O[df][r] *= alpha;
            O4[0] *= alpha;
            Mv = mnew;
        }
#pragma unroll
        for (int jf = 0; jf < 4; jf++)
#pragma unroll
            for (int r = 0; r < 4; r++)
                sf[jf][r] = exp2v(sf[jf][r] - Mv);

        // pack P^T -> per-wave LDS, lane writes 8 u32 contiguous
        *(uint2*)(pwr + 0) = make_uint2(cvt_pk_bf(sf[0][0], sf[0][1]), cvt_pk_bf(sf[0][2], sf[0][3]));
        *(uint2*)(pwr + 2) = make_uint2(cvt_pk_bf(sf[1][0], sf[1][1]), cvt_pk_bf(sf[1][2], sf[1][3]));
        *(uint2*)(pwr + 4) = make_uint2(cvt_pk_bf(sf[2][0], sf[2][1]), cvt_pk_bf(sf[2][2], sf[2][3]));
        *(uint2*)(pwr + 6) = make_uint2(cvt_pk_bf(sf[3][0], sf[3][1]), cvt_pk_bf(sf[3][2], sf[3][3]));

        // O^T += V^T P^T ; L-row via ones-MFMA
        __builtin_amdgcn_s_setprio(1);
#pragma unroll
        for (int kk = 0; kk < 2; kk++) {
            uint2 a2 = *(const uint2*)(prd + pbase + kk * 4);
            uint2 c2 = *(const uint2*)(prd + pbase + kk * 4 + 8);
            union { uint2 p[2]; s16x8 v; } pu;
            pu.p[0] = a2; pu.p[1] = c2;
            s16x8 pf = pu.v;
            int co = ((kk * 4 + lg) ^ (lr & 7)) * 8;
            O4 = __builtin_amdgcn_mfma_f32_16x16x32_bf16(onesf, pf, O4, 0, 0, 0);
#pragma unroll
            for (int df = 0; df < 4; df++) {
                s16x8 vf = *(const s16x8*)&Vl[(df * 16 + lr) * 64 + co];
                O[df] = __builtin_amdgcn_mfma_f32_16x16x32_bf16(vf, pf, O[df], 0, 0, 0);
            }
        }
        __builtin_amdgcn_s_setprio(0);
        __syncthreads();   // drains my prefetch loads; fences all waves' reads of buf cur
        cur ^= 1;
    }

    // L for q=lr sits in lane lr (lg==0), component 0 of O4
    float Lq = __shfl(O4[0], lr, 64);
    float rl = 1.0f / Lq;

    // epilogue: normalize, transpose via reused KV slab (per-wave, intra-wave sync only)
    unsigned short* slab = (unsigned short*)KV + wid * 1152;   // 16 x 72
#pragma unroll
    for (int df = 0; df < 4; df++) {
        uint2 w2 = make_uint2(cvt_pk_bf(O[df][0] * rl, O[df][1] * rl),
                              cvt_pk_bf(O[df][2] * rl, O[df][3] * rl));
        *(uint2*)&slab[lr * 72 + df * 16 + lg * 4] = w2;
    }
    int orow = lane >> 2, part = lane & 3;
    const s16x8* src = (const s16x8*)&slab[orow * 72 + part * 16];
    s16x8 o0 = src[0], o1 = src[1];               // FULL 16 shorts (round-4 bug: o1 was dropped)
    unsigned short* gdst = aout + (size_t)(b * Nn + n0 + orow) * 1024 + h * 64 + part * 16;
    *(s16x8*)gdst = o0;
    *((s16x8*)gdst + 1) = o1;
}

// ---------------- launch ----------------
extern "C" void kernel_launch(void* const* d_in, const int* in_sizes, int n_in,
                              void* d_out, int out_size, void* d_ws, size_t ws_size,
                              hipStream_t stream) {
    const float* x    = (const float*)d_in[0];
    const float* ctx  = (const float*)d_in[1];
    const float* g1   = (const float*)d_in[2];
    const float* Wq   = (const float*)d_in[3];
    const float* Wkv  = (const float*)d_in[4];
    const float* nkv  = (const float*)d_in[5];
    const float* ctxg = (const float*)d_in[6];
    const float* ctxb = (const float*)d_in[7];
    const float* Wc   = (const float*)d_in[8];
    const float* bc   = (const float*)d_in[9];
    const float* Wout = (const float*)d_in[10];
    const float* g2   = (const float*)d_in[11];
    float* out = (float*)d_out;

    char* w = (char*)d_ws;
    unsigned short* h_    = (unsigned short*)w; w += (size_t)4096 * 1024 * 2;
    unsigned short* ch    = (unsigned short*)w; w += (size_t)512 * 1024 * 2;
    unsigned short* WqkvT = (unsigned short*)w; w += (size_t)1152 * 1024 * 2;
    unsigned short* WcT   = (unsigned short*)w; w += (size_t)128 * 1024 * 2;
    unsigned short* WoutT = (unsigned short*)w; w += (size_t)1024 * 1024 * 2;
    unsigned short* qkv   = (unsigned short*)w; w += (size_t)4096 * 1152 * 2;
    unsigned short* ckv   = (unsigned short*)w; w += (size_t)512 * 128 * 2;
    unsigned short* Kb    = (unsigned short*)w; w += (size_t)Bb * JP * 64 * 2;
    unsigned short* Vt    = (unsigned short*)w; w += (size_t)Bb * 64 * JP * 2;
    unsigned short* aout  = (unsigned short*)w; w += (size_t)4096 * 1024 * 2;
    float* preout         = (float*)w;          w += (size_t)4096 * 1024 * 4;

    // fold softmax scale AND log2(e) into Wq so QK^T lands in exp2 domain
    const float qscale = 0.125f * 1.4426950408889634f;

    // weight transposes (one launch)
    k_transpose_all<<<dim3(72, 32), 256, 0, stream>>>(Wq, Wkv, Wc, Wout, WqkvT, WcT, WoutT, qscale);

    // input layernorms (one launch)
    k_ln_in<<<4608, 256, 0, stream>>>(x, ctx, g1, ctxg, ctxb, h_, ch);

    // projections (64x64 tiles)
    k_gemm_bt<1><<<dim3(18, 64), 256, 0, stream>>>(h_, WqkvT, qkv, 4096, 1152, 1024);
    k_gemm_bt<1><<<dim3(2, 8),   256, 0, stream>>>(ch, WcT,   ckv, 512,  128,  1024);

    // build K (row-major) and V^T
    k_assemble_kv<<<(Bb * JP * 64) / 256, 256, 0, stream>>>(qkv, ckv, nkv, bc, Kb, Vt);

    // attention
    k_attn<<<Bb * Hh * (Nn / 64), 256, 0, stream>>>(qkv, Kb, Vt, aout);

    // output projection + final LN
    k_gemm_bt<0><<<dim3(16, 64), 256, 0, stream>>>(aout, WoutT, preout, 4096, 1024, 1024);
    k_ln_out<<<4096, 256, 0, stream>>>(preout, g2, out);
}

// Round 6
// 134.788 us; speedup vs baseline: 2.1415x; 1.2237x over previous
//
#include <hip/hip_runtime.h>

typedef __attribute__((ext_vector_type(4))) float  f32x4;
typedef __attribute__((ext_vector_type(8))) short  s16x8;

#define DEVI __device__ __forceinline__

// ---------------- constants ----------------
constexpr int Bb   = 2;
constexpr int Nn   = 2048;
constexpr int Hh   = 16;
constexpr int DHc  = 64;
constexpr int CTXN = 256;
constexpr int Jv   = Nn + 1 + CTXN;   // 2305 valid kv tokens
constexpr int JP   = 2368;            // padded to 37*64
constexpr int QKVN = Hh*DHc + 2*DHc;  // 1152

// ---------------- helpers ----------------
DEVI unsigned short f2bf(float f) {
    union { float f; unsigned u; } v; v.f = f;
    unsigned r = v.u + 0x7fffu + ((v.u >> 16) & 1u);
    return (unsigned short)(r >> 16);
}
DEVI float bf2f(unsigned short h) {
    union { unsigned u; float f; } v; v.u = ((unsigned)h) << 16;
    return v.f;
}
DEVI unsigned cvt_pk_bf(float lo, float hi) {   // dst.lo=bf16(lo), dst.hi=bf16(hi)
    unsigned r;
    asm("v_cvt_pk_bf16_f32 %0, %1, %2" : "=v"(r) : "v"(lo), "v"(hi));
    return r;
}
DEVI float exp2v(float x) {                      // v_exp_f32 = 2^x
    float r;
    asm("v_exp_f32 %0, %1" : "=v"(r) : "v"(x));
    return r;
}
// async global->LDS, 16B per lane; LDS dest = uniform base + lane*16 (linear)
DEVI void gl_lds16(const void* g, void* l) {
    __builtin_amdgcn_global_load_lds(
        (__attribute__((address_space(1))) void*)g,
        (__attribute__((address_space(3))) void*)l,
        16, 0, 0);
}

// ---------------- all weight transposes in one launch ----------------
// f32 [1024][C] -> bf16 [C][1024] (B^T layout), optional scale
__global__ __launch_bounds__(256) void k_transpose_all(const float* __restrict__ Wq,
                                                       const float* __restrict__ Wkv,
                                                       const float* __restrict__ Wc,
                                                       const float* __restrict__ Wout,
                                                       unsigned short* __restrict__ WqkvT,
                                                       unsigned short* __restrict__ WcT,
                                                       unsigned short* __restrict__ WoutT,
                                                       float qscale) {
    __shared__ float tile[32][33];
    int bx = blockIdx.x;
    const float* in; unsigned short* out; int C; float scale; int cb;
    if (bx < 32)      { in = Wq;   out = WqkvT;               C = 1024; scale = qscale; cb = bx; }
    else if (bx < 36) { in = Wkv;  out = WqkvT + 1024 * 1024; C = 128;  scale = 1.0f;  cb = bx - 32; }
    else if (bx < 40) { in = Wc;   out = WcT;                 C = 128;  scale = 1.0f;  cb = bx - 36; }
    else              { in = Wout; out = WoutT;               C = 1024; scale = 1.0f;  cb = bx - 40; }
    int tx = threadIdx.x & 31, ty = threadIdx.x >> 5;   // 32 x 8
    int r0 = blockIdx.y * 32, c0 = cb * 32;
#pragma unroll
    for (int i = 0; i < 32; i += 8)
        tile[ty + i][tx] = in[(size_t)(r0 + ty + i) * C + c0 + tx];
    __syncthreads();
#pragma unroll
    for (int i = 0; i < 32; i += 8)
        out[(size_t)(c0 + ty + i) * 1024 + r0 + tx] = f2bf(tile[tx][ty + i] * scale);
}

// ---------------- merged input LayerNorms (x rows 0..4095, ctx rows 4096..4607) ----------------
__global__ __launch_bounds__(256) void k_ln_in(const float* __restrict__ x,
                                               const float* __restrict__ ctx,
                                               const float* __restrict__ g1,
                                               const float* __restrict__ cg,
                                               const float* __restrict__ cb,
                                               unsigned short* __restrict__ h,
                                               unsigned short* __restrict__ ch) {
    int row = blockIdx.x, tid = threadIdx.x;
    bool isx = row < 4096;
    const float* rp = isx ? x + (size_t)row * 1024 : ctx + (size_t)(row - 4096) * 1024;
    const float* g  = isx ? g1 : cg;
    float eps = isx ? 1e-5f : 1e-6f;
    unsigned short* o = isx ? h + (size_t)row * 1024 : ch + (size_t)(row - 4096) * 1024;

    f32x4 v = *(const f32x4*)(rp + tid * 4);
    float s = v.x + v.y + v.z + v.w;
    float q = v.x * v.x + v.y * v.y + v.z * v.z + v.w * v.w;
#pragma unroll
    for (int m = 32; m; m >>= 1) { s += __shfl_down(s, m, 64); q += __shfl_down(q, m, 64); }
    __shared__ float ss[4], sq[4];
    int wid = tid >> 6, lane = tid & 63;
    if (lane == 0) { ss[wid] = s; sq[wid] = q; }
    __syncthreads();
    s = ss[0] + ss[1] + ss[2] + ss[3];
    q = sq[0] + sq[1] + sq[2] + sq[3];
    float mean = s * (1.0f / 1024.0f);
    float var  = q * (1.0f / 1024.0f) - mean * mean;
    float rstd = rsqrtf(var + eps);
    f32x4 gg = *(const f32x4*)(g + tid * 4);
    f32x4 r;
#pragma unroll
    for (int e = 0; e < 4; e++) r[e] = (v[e] - mean) * rstd * gg[e];
    if (!isx) {
        f32x4 bb = *(const f32x4*)(cb + tid * 4);
#pragma unroll
        for (int e = 0; e < 4; e++) r[e] += bb[e];
    }
    uint2 ov = make_uint2(cvt_pk_bf(r[0], r[1]), cvt_pk_bf(r[2], r[3]));
    *(uint2*)(o + tid * 4) = ov;
}

// ---------------- final LayerNorm (f32 out) ----------------
__global__ __launch_bounds__(256) void k_ln_out(const float* __restrict__ in,
                                                const float* __restrict__ g,
                                                float* __restrict__ out) {
    int row = blockIdx.x, tid = threadIdx.x;
    const float* rp = in + (size_t)row * 1024;
    f32x4 v = *(const f32x4*)(rp + tid * 4);
    float s = v.x + v.y + v.z + v.w;
    float q = v.x * v.x + v.y * v.y + v.z * v.z + v.w * v.w;
#pragma unroll
    for (int m = 32; m; m >>= 1) { s += __shfl_down(s, m, 64); q += __shfl_down(q, m, 64); }
    __shared__ float ss[4], sq[4];
    int wid = tid >> 6, lane = tid & 63;
    if (lane == 0) { ss[wid] = s; sq[wid] = q; }
    __syncthreads();
    s = ss[0] + ss[1] + ss[2] + ss[3];
    q = sq[0] + sq[1] + sq[2] + sq[3];
    float mean = s * (1.0f / 1024.0f);
    float var  = q * (1.0f / 1024.0f) - mean * mean;
    float rstd = rsqrtf(var + 1e-5f);
    f32x4 gg = *(const f32x4*)(g + tid * 4);
    f32x4 r;
#pragma unroll
    for (int e = 0; e < 4; e++) r[e] = (v[e] - mean) * rstd * gg[e];
    *(f32x4*)(out + (size_t)row * 1024 + tid * 4) = r;
}

// ---------------- GEMM: C[M][N] = A[M][K](bf16) * BT[N][K](bf16)^T ----------------
// 64x64 tile, BK=64, 4 waves (2x2, wave=32x32), double-buffered global_load_lds staging.
template<int OUT_BF16>
__global__ __launch_bounds__(256) void k_gemm_bt(const unsigned short* __restrict__ A,
                                                 const unsigned short* __restrict__ BT,
                                                 void* __restrict__ C,
                                                 int M, int N, int K) {
    __shared__ unsigned short SA[2][64 * 64];
    __shared__ unsigned short SB[2][64 * 64];
    int tid = threadIdx.x;
    int bn = blockIdx.x, bm = blockIdx.y;
    int wid = tid >> 6, lane = tid & 63;
    int wm = wid >> 1, wn = wid & 1;
    int lr = lane & 15, lg = lane >> 4;
    int r8 = lane >> 3;                 // 0..7
    int sl = (lane & 7) ^ r8;           // pre-swizzled source slot

    const unsigned short* Ag = A  + (size_t)(bm * 64 + wid * 16 + r8) * K + sl * 8;
    const unsigned short* Bg = BT + (size_t)(bn * 64 + wid * 16 + r8) * K + sl * 8;

    auto stage = [&](int k0, int buf) {
#pragma unroll
        for (int i = 0; i < 2; i++) {
            gl_lds16(Ag + (size_t)i * 8 * K + k0, &SA[buf][wid * 1024 + i * 512]);
            gl_lds16(Bg + (size_t)i * 8 * K + k0, &SB[buf][wid * 1024 + i * 512]);
        }
    };

    f32x4 acc[2][2] = {};
    int nk = K >> 6;
    stage(0, 0);
    __syncthreads();
    int cur = 0;
    for (int s = 0; s < nk; ++s) {
        if (s + 1 < nk) stage((s + 1) << 6, cur ^ 1);
        const unsigned short* Al = &SA[cur][0];
        const unsigned short* Bl = &SB[cur][0];
#pragma unroll
        for (int kk = 0; kk < 2; kk++) {
            int co = ((kk * 4 + lg) ^ (lr & 7)) * 8;
            s16x8 af[2], bf[2];
#pragma unroll
            for (int mi = 0; mi < 2; mi++)
                af[mi] = *(const s16x8*)&Al[(wm * 32 + mi * 16 + lr) * 64 + co];
#pragma unroll
            for (int ni = 0; ni < 2; ni++)
                bf[ni] = *(const s16x8*)&Bl[(wn * 32 + ni * 16 + lr) * 64 + co];
#pragma unroll
            for (int mi = 0; mi < 2; mi++)
#pragma unroll
                for (int ni = 0; ni < 2; ni++)
                    acc[mi][ni] = __builtin_amdgcn_mfma_f32_16x16x32_bf16(af[mi], bf[ni], acc[mi][ni], 0, 0, 0);
        }
        __syncthreads();
        cur ^= 1;
    }
#pragma unroll
    for (int mi = 0; mi < 2; mi++)
#pragma unroll
        for (int r = 0; r < 4; r++) {
            int row = bm * 64 + wm * 32 + mi * 16 + lg * 4 + r;
#pragma unroll
            for (int ni = 0; ni < 2; ni++) {
                int col = bn * 64 + wn * 32 + ni * 16 + lr;
                float val = acc[mi][ni][r];
                if (OUT_BF16)
                    ((unsigned short*)C)[(size_t)row * N + col] = f2bf(val);
                else
                    ((float*)C)[(size_t)row * N + col] = val;
            }
        }
}

// ---------------- assemble K (row-major [b][j][d]) and V^T ([b][d][JP]) ----------------
__global__ __launch_bounds__(256) void k_assemble_kv(const unsigned short* __restrict__ qkv,
                                                     const unsigned short* __restrict__ ckv,
                                                     const float* __restrict__ nkv,
                                                     const float* __restrict__ bc,
                                                     unsigned short* __restrict__ Kb,
                                                     unsigned short* __restrict__ Vt) {
    int idx = blockIdx.x * 256 + threadIdx.x;   // Bb*JP*64 total
    int d = idx & 63;
    int j = (idx >> 6) % JP;
    int b = idx / (64 * JP);
    float kv, vv;
    if (j < Nn) {
        const unsigned short* r = qkv + (size_t)(b * Nn + j) * QKVN + Hh * DHc;
        kv = bf2f(r[d]); vv = bf2f(r[64 + d]);
    } else if (j == Nn) {
        kv = nkv[d]; vv = nkv[64 + d];
    } else if (j < Jv) {
        const unsigned short* r = ckv + (size_t)(b * CTXN + (j - Nn - 1)) * 128;
        kv = bf2f(r[d]) + bc[d]; vv = bf2f(r[64 + d]) + bc[64 + d];
    } else {
        kv = 0.0f; vv = 0.0f;
    }
    Kb[((size_t)b * JP + j) * 64 + d] = f2bf(kv);
    Vt[((size_t)b * 64 + d) * JP + j] = f2bf(vv);
}

// ---------------- flash attention: 8 waves / 128 q-rows per block ----------------
// grid: b(2) x h(16) x qtile(16).  block = 512 = 8 waves; wave owns 16 q-rows (q = n0 + lr).
// K/V staged once per block and shared by all 128 q rows (16 heads share one kv head).
__global__ __launch_bounds__(512) void k_attn(const unsigned short* __restrict__ qkv,
                                              const unsigned short* __restrict__ Kb,
                                              const unsigned short* __restrict__ Vt,
                                              unsigned short* __restrict__ aout) {
    __shared__ unsigned short KV[2][2][64 * 64];  // [buf][0=K rows j][1=V^T rows d]
    __shared__ unsigned       Pp[8][16][34];      // per-wave packed P^T

    int bid = blockIdx.x;
    int qt = bid & 15, h = (bid >> 4) & 15, b = bid >> 8;
    int tid = threadIdx.x, wid = tid >> 6, lane = tid & 63;
    int lr = lane & 15, lg = lane >> 4;
    int n0 = qt * 128 + wid * 16;
    int r8 = lane >> 3;
    int sl = (lane & 7) ^ r8;

    // Q fragments (B-operand): col=lr -> q row n0+lr, k = kk*32 + lg*8 + e
    s16x8 qf[2];
#pragma unroll
    for (int kk = 0; kk < 2; kk++)
        qf[kk] = *(const s16x8*)(qkv + (size_t)(b * Nn + n0 + lr) * QKVN + h * 64 + kk * 32 + lg * 8);

    // ones A-fragment: row 0 = 1.0, rows 1..15 = 0  (for L = colsum(P) via MFMA)
    s16x8 onesf;
    {
        short o = (lr == 0) ? (short)0x3F80 : (short)0;
#pragma unroll
        for (int e = 0; e < 8; e++) onesf[e] = o;
    }

    f32x4 O[4] = {};        // O^T frags: col=lr=q, row d = df*16 + lg*4 + r
    f32x4 O4 = {};          // L accumulator (row 0 = sum of P)
    float Mv = -1e30f;

    // staging: wave w covers rows w*8 + r8 (one 16B chunk per lane, 1KB per wave)
    const unsigned short* Kg = Kb + ((size_t)b * JP + wid * 8 + r8) * 64 + sl * 8;
    const unsigned short* Vg = Vt + ((size_t)b * 64 + wid * 8 + r8) * JP + sl * 8;

    auto stage = [&](int t, int buf) {
        gl_lds16(Kg + (size_t)t * 4096, &KV[buf][0][wid * 512]);
        gl_lds16(Vg + (size_t)t * 64,   &KV[buf][1][wid * 512]);
    };

    int pbase = ((2 * lg) & 3) * 8 + (lg >> 1) * 2;
    unsigned* pwr = &Pp[wid][lr][lg * 8];
    const unsigned* prd = &Pp[wid][lr][0];

    stage(0, 0);
    __syncthreads();
    int cur = 0;
#pragma unroll 1
    for (int t = 0; t < 37; ++t) {
        if (t < 36) stage(t + 1, cur ^ 1);
        const unsigned short* Kl = &KV[cur][0][0];
        const unsigned short* Vl = &KV[cur][1][0];

        // S^T = K Q^T : lane holds col=lr=q-row, rows j = t*64 + jf*16 + lg*4 + r  (log2 units)
        f32x4 sf[4] = {};
        __builtin_amdgcn_s_setprio(1);
#pragma unroll
        for (int kk = 0; kk < 2; kk++) {
            int co = ((kk * 4 + lg) ^ (lr & 7)) * 8;
#pragma unroll
            for (int jf = 0; jf < 4; jf++) {
                s16x8 kf = *(const s16x8*)&Kl[(jf * 16 + lr) * 64 + co];
                sf[jf] = __builtin_amdgcn_mfma_f32_16x16x32_bf16(kf, qf[kk], sf[jf], 0, 0, 0);
            }
        }
        __builtin_amdgcn_s_setprio(0);
        if (t == 36) {   // mask padded tokens (uniform branch)
#pragma unroll
            for (int jf = 0; jf < 4; jf++)
#pragma unroll
                for (int r = 0; r < 4; r++)
                    if (36 * 64 + jf * 16 + lg * 4 + r >= Jv) sf[jf][r] = -1e30f;
        }

        // row max (3-ary groupings -> v_max3)
        float t0 = fmaxf(fmaxf(sf[0][0], sf[0][1]), sf[0][2]);
        float t1 = fmaxf(fmaxf(sf[0][3], sf[1][0]), sf[1][1]);
        float t2 = fmaxf(fmaxf(sf[1][2], sf[1][3]), sf[2][0]);
        float t3 = fmaxf(fmaxf(sf[2][1], sf[2][2]), sf[2][3]);
        float t4 = fmaxf(fmaxf(sf[3][0], sf[3][1]), sf[3][2]);
        float t5 = fmaxf(fmaxf(t0, t1), sf[3][3]);
        float pm = fmaxf(fmaxf(t2, t3), fmaxf(t4, t5));
        pm = fmaxf(pm, __shfl_xor(pm, 16, 64));
        pm = fmaxf(pm, __shfl_xor(pm, 32, 64));
        if (!__all(pm - Mv <= 8.0f)) {        // defer-max: rescale only on real growth
            float mnew = fmaxf(Mv, pm);
            float alpha = exp2v(Mv - mnew);
#pragma unroll
            for (int df = 0; df < 4; df++)
#pragma unroll
                for (int r = 0; r < 4; r++) O[df][r] *= alpha;
            O4[0] *= alpha;
            Mv = mnew;
        }
#pragma unroll
        for (int jf = 0; jf < 4; jf++)
#pragma unroll
            for (int r = 0; r < 4; r++)
                sf[jf][r] = exp2v(sf[jf][r] - Mv);

        // pack P^T -> per-wave LDS, lane writes 8 u32 contiguous
        *(uint2*)(pwr + 0) = make_uint2(cvt_pk_bf(sf[0][0], sf[0][1]), cvt_pk_bf(sf[0][2], sf[0][3]));
        *(uint2*)(pwr + 2) = make_uint2(cvt_pk_bf(sf[1][0], sf[1][1]), cvt_pk_bf(sf[1][2], sf[1][3]));
        *(uint2*)(pwr + 4) = make_uint2(cvt_pk_bf(sf[2][0], sf[2][1]), cvt_pk_bf(sf[2][2], sf[2][3]));
        *(uint2*)(pwr + 6) = make_uint2(cvt_pk_bf(sf[3][0], sf[3][1]), cvt_pk_bf(sf[3][2], sf[3][3]));

        // O^T += V^T P^T ; L-row via ones-MFMA
        __builtin_amdgcn_s_setprio(1);
#pragma unroll
        for (int kk = 0; kk < 2; kk++) {
            uint2 a2 = *(const uint2*)(prd + pbase + kk * 4);
            uint2 c2 = *(const uint2*)(prd + pbase + kk * 4 + 8);
            union { uint2 p[2]; s16x8 v; } pu;
            pu.p[0] = a2; pu.p[1] = c2;
            s16x8 pf = pu.v;
            int co = ((kk * 4 + lg) ^ (lr & 7)) * 8;
            O4 = __builtin_amdgcn_mfma_f32_16x16x32_bf16(onesf, pf, O4, 0, 0, 0);
#pragma unroll
            for (int df = 0; df < 4; df++) {
                s16x8 vf = *(const s16x8*)&Vl[(df * 16 + lr) * 64 + co];
                O[df] = __builtin_amdgcn_mfma_f32_16x16x32_bf16(vf, pf, O[df], 0, 0, 0);
            }
        }
        __builtin_amdgcn_s_setprio(0);
        __syncthreads();   // drains my prefetch loads; fences all waves' reads of buf cur
        cur ^= 1;
    }

    // L for q=lr sits in lane lr (lg==0), component 0 of O4
    float Lq = __shfl(O4[0], lr, 64);
    float rl = 1.0f / Lq;

    // epilogue: normalize, transpose via reused KV slab (per-wave region, intra-wave only)
    unsigned short* slab = (unsigned short*)KV + wid * 1152;   // 16 x 72
#pragma unroll
    for (int df = 0; df < 4; df++) {
        uint2 w2 = make_uint2(cvt_pk_bf(O[df][0] * rl, O[df][1] * rl),
                              cvt_pk_bf(O[df][2] * rl, O[df][3] * rl));
        *(uint2*)&slab[lr * 72 + df * 16 + lg * 4] = w2;
    }
    int orow = lane >> 2, part = lane & 3;
    const s16x8* src = (const s16x8*)&slab[orow * 72 + part * 16];
    s16x8 o0 = src[0], o1 = src[1];
    unsigned short* gdst = aout + (size_t)(b * Nn + n0 + orow) * 1024 + h * 64 + part * 16;
    *(s16x8*)gdst = o0;
    *((s16x8*)gdst + 1) = o1;
}

// ---------------- launch ----------------
extern "C" void kernel_launch(void* const* d_in, const int* in_sizes, int n_in,
                              void* d_out, int out_size, void* d_ws, size_t ws_size,
                              hipStream_t stream) {
    const float* x    = (const float*)d_in[0];
    const float* ctx  = (const float*)d_in[1];
    const float* g1   = (const float*)d_in[2];
    const float* Wq   = (const float*)d_in[3];
    const float* Wkv  = (const float*)d_in[4];
    const float* nkv  = (const float*)d_in[5];
    const float* ctxg = (const float*)d_in[6];
    const float* ctxb = (const float*)d_in[7];
    const float* Wc   = (const float*)d_in[8];
    const float* bc   = (const float*)d_in[9];
    const float* Wout = (const float*)d_in[10];
    const float* g2   = (const float*)d_in[11];
    float* out = (float*)d_out;

    char* w = (char*)d_ws;
    unsigned short* h_    = (unsigned short*)w; w += (size_t)4096 * 1024 * 2;
    unsigned short* ch    = (unsigned short*)w; w += (size_t)512 * 1024 * 2;
    unsigned short* WqkvT = (unsigned short*)w; w += (size_t)1152 * 1024 * 2;
    unsigned short* WcT   = (unsigned short*)w; w += (size_t)128 * 1024 * 2;
    unsigned short* WoutT = (unsigned short*)w; w += (size_t)1024 * 1024 * 2;
    unsigned short* qkv   = (unsigned short*)w; w += (size_t)4096 * 1152 * 2;
    unsigned short* ckv   = (unsigned short*)w; w += (size_t)512 * 128 * 2;
    unsigned short* Kb    = (unsigned short*)w; w += (size_t)Bb * JP * 64 * 2;
    unsigned short* Vt    = (unsigned short*)w; w += (size_t)Bb * 64 * JP * 2;
    unsigned short* aout  = (unsigned short*)w; w += (size_t)4096 * 1024 * 2;
    float* preout         = (float*)w;          w += (size_t)4096 * 1024 * 4;

    // fold softmax scale AND log2(e) into Wq so QK^T lands in exp2 domain
    const float qscale = 0.125f * 1.4426950408889634f;

    // weight transposes (one launch)
    k_transpose_all<<<dim3(72, 32), 256, 0, stream>>>(Wq, Wkv, Wc, Wout, WqkvT, WcT, WoutT, qscale);

    // input layernorms (one launch)
    k_ln_in<<<4608, 256, 0, stream>>>(x, ctx, g1, ctxg, ctxb, h_, ch);

    // projections (64x64 tiles)
    k_gemm_bt<1><<<dim3(18, 64), 256, 0, stream>>>(h_, WqkvT, qkv, 4096, 1152, 1024);
    k_gemm_bt<1><<<dim3(2, 8),   256, 0, stream>>>(ch, WcT,   ckv, 512,  128,  1024);

    // build K (row-major) and V^T
    k_assemble_kv<<<(Bb * JP * 64) / 256, 256, 0, stream>>>(qkv, ckv, nkv, bc, Kb, Vt);

    // attention: 512 threads, 128 q-rows per block, K/V staged once per block
    k_attn<<<Bb * Hh * (Nn / 128), 512, 0, stream>>>(qkv, Kb, Vt, aout);

    // output projection + final LN
    k_gemm_bt<0><<<dim3(16, 64), 256, 0, stream>>>(aout, WoutT, preout, 4096, 1024, 1024);
    k_ln_out<<<4096, 256, 0, stream>>>(preout, g2, out);
}